// Round 2
// baseline (475.270 us; speedup 1.0000x reference)
//
#include <hip/hip_runtime.h>

typedef unsigned short ushort_t;
typedef unsigned int   uint_t;
typedef float  float4v __attribute__((ext_vector_type(4)));
typedef __bf16 bf16x8  __attribute__((ext_vector_type(8)));

#define Bsz 32
#define Tsz 1024
#define Din 512
#define Hsz 512
#define Mtot (Bsz * Tsz)                 // 32768
#define ELEMS ((size_t)Mtot * Hsz)       // 16777216 (== Mtot*Din, since Din==Hsz)

// ===========================================================================
// Pass 1: exact 3-way bf16 truncation split.
//   A [Mtot,Din] fp32 -> A0,A1,A2 bf16 (same layout)
//   W [Din,Hsz] fp32  -> B0,B1,B2 bf16 TRANSPOSED [Hsz][Din] (n-major, k-contig)
// Truncation split is exact: x == h0+h1+h2 bitwise (bf16 has fp32's exponent).
// ===========================================================================
__device__ __forceinline__ void split3(float c, uint_t& h0, uint_t& h1, uint_t& h2)
{
    uint_t t0 = __float_as_uint(c) & 0xFFFF0000u;
    float  r1 = c - __uint_as_float(t0);
    uint_t t1 = __float_as_uint(r1) & 0xFFFF0000u;
    float  r2 = r1 - __uint_as_float(t1);
    uint_t t2 = __float_as_uint(r2) & 0xFFFF0000u;
    h0 = t0 >> 16; h1 = t1 >> 16; h2 = t2 >> 16;
}

__global__ __launch_bounds__(256) void split_bf16x3(
    const float* __restrict__ A, const float* __restrict__ W,
    ushort_t* __restrict__ A0, ushort_t* __restrict__ A1, ushort_t* __restrict__ A2,
    ushort_t* __restrict__ B0, ushort_t* __restrict__ B1, ushort_t* __restrict__ B2)
{
    const int bid = blockIdx.x, tid = threadIdx.x;
    if (bid < 4096) {                       // A split: 4096*256*4 float4 == ELEMS/4
        const float4* Af = (const float4*)A;
#pragma unroll
        for (int q = 0; q < 4; ++q) {
            const size_t i = (size_t)bid * 1024 + q * 256 + tid;
            float4 x = Af[i];
            const float c[4] = {x.x, x.y, x.z, x.w};
            uint_t h0[4], h1[4], h2[4];
#pragma unroll
            for (int j = 0; j < 4; ++j) split3(c[j], h0[j], h1[j], h2[j]);
            *(uint2*)(A0 + 4 * i) = make_uint2(h0[0] | (h0[1] << 16), h0[2] | (h0[3] << 16));
            *(uint2*)(A1 + 4 * i) = make_uint2(h1[0] | (h1[1] << 16), h1[2] | (h1[3] << 16));
            *(uint2*)(A2 + 4 * i) = make_uint2(h2[0] | (h2[1] << 16), h2[2] | (h2[3] << 16));
        }
    } else {                                // W split+transpose: 256 blocks
        const int f4 = (bid - 4096) * 256 + tid;        // 0..65535
        const int k  = f4 >> 7;
        const int n4 = (f4 & 127) << 2;
        float4 x = *(const float4*)(W + (size_t)k * Hsz + n4);
        const float c[4] = {x.x, x.y, x.z, x.w};
#pragma unroll
        for (int j = 0; j < 4; ++j) {
            uint_t h0, h1, h2;
            split3(c[j], h0, h1, h2);
            const size_t o = (size_t)(n4 + j) * Din + k;  // transposed
            B0[o] = (ushort_t)h0; B1[o] = (ushort_t)h1; B2[o] = (ushort_t)h2;
        }
    }
}

// ===========================================================================
// Pass 2: bf16x3 MFMA GEMM.  C[m,n] = sum_{6 limb pairs} Ai[m,:]*Bj[n,:] + bias
// 128x128 tile, 4 waves (2x2 of 64x64), BK=32, mfma_f32_16x16x32_bf16.
// LDS stride 40 bf16 (80 B) -> frag ds_read_b128 is 2-way-conflict only (free).
// ===========================================================================
__global__ __launch_bounds__(256) void gemm_bf16x3(
    const ushort_t* __restrict__ A0, const ushort_t* __restrict__ A1,
    const ushort_t* __restrict__ A2,
    const ushort_t* __restrict__ B0, const ushort_t* __restrict__ B1,
    const ushort_t* __restrict__ B2,
    const float* __restrict__ bias, float* __restrict__ C)
{
    __shared__ ushort_t As[3][128][40];
    __shared__ ushort_t Bs[3][128][40];

    const int tid  = threadIdx.x;
    const int m0   = blockIdx.y * 128;
    const int n0   = blockIdx.x * 128;
    const int wave = tid >> 6, lane = tid & 63;
    const int wm = (wave & 1) * 64, wn = (wave >> 1) * 64;
    const int lr = lane & 15, lg = lane >> 4;

    // staging mapping: per limb, tile is 128 rows x 32 k (64 B/row = 4 x 16 B)
    const int srow = tid >> 2;              // 0..63 (+64 for second half)
    const int skq  = tid & 3;               // 16B-unit within row
    const ushort_t* ap[3] = {A0, A1, A2};
    const ushort_t* bp[3] = {B0, B1, B2};

    float4v acc[4][4];
#pragma unroll
    for (int i = 0; i < 4; ++i)
#pragma unroll
        for (int j = 0; j < 4; ++j) acc[i][j] = (float4v)0.f;

    uint4 rA[3][2], rB[3][2];
#pragma unroll
    for (int i = 0; i < 3; ++i)
#pragma unroll
        for (int h = 0; h < 2; ++h) {
            rA[i][h] = *(const uint4*)(ap[i] + (size_t)(m0 + srow + h * 64) * Din + skq * 8);
            rB[i][h] = *(const uint4*)(bp[i] + (size_t)(n0 + srow + h * 64) * Din + skq * 8);
        }

    for (int kc = 0; kc < Din; kc += 32) {
        // regs (chunk kc) -> LDS
#pragma unroll
        for (int i = 0; i < 3; ++i)
#pragma unroll
            for (int h = 0; h < 2; ++h) {
                *(uint4*)&As[i][srow + h * 64][skq * 8] = rA[i][h];
                *(uint4*)&Bs[i][srow + h * 64][skq * 8] = rB[i][h];
            }
        __syncthreads();

        if (kc + 32 < Din) {                // prefetch chunk kc+32 (hides under MFMA)
#pragma unroll
            for (int i = 0; i < 3; ++i)
#pragma unroll
                for (int h = 0; h < 2; ++h) {
                    rA[i][h] = *(const uint4*)(ap[i] + (size_t)(m0 + srow + h * 64) * Din + kc + 32 + skq * 8);
                    rB[i][h] = *(const uint4*)(bp[i] + (size_t)(n0 + srow + h * 64) * Din + kc + 32 + skq * 8);
                }
        }

        bf16x8 afr[3][4];
#pragma unroll
        for (int i = 0; i < 3; ++i)
#pragma unroll
            for (int mf = 0; mf < 4; ++mf)
                afr[i][mf] = *(const bf16x8*)&As[i][wm + mf * 16 + lr][lg * 8];

#pragma unroll
        for (int nf = 0; nf < 4; ++nf) {
            bf16x8 b0 = *(const bf16x8*)&Bs[0][wn + nf * 16 + lr][lg * 8];
            bf16x8 b1 = *(const bf16x8*)&Bs[1][wn + nf * 16 + lr][lg * 8];
            bf16x8 b2 = *(const bf16x8*)&Bs[2][wn + nf * 16 + lr][lg * 8];
#pragma unroll
            for (int mf = 0; mf < 4; ++mf) {
                float4v a = acc[mf][nf];
                a = __builtin_amdgcn_mfma_f32_16x16x32_bf16(afr[0][mf], b0, a, 0, 0, 0);
                a = __builtin_amdgcn_mfma_f32_16x16x32_bf16(afr[0][mf], b1, a, 0, 0, 0);
                a = __builtin_amdgcn_mfma_f32_16x16x32_bf16(afr[1][mf], b0, a, 0, 0, 0);
                a = __builtin_amdgcn_mfma_f32_16x16x32_bf16(afr[1][mf], b1, a, 0, 0, 0);
                a = __builtin_amdgcn_mfma_f32_16x16x32_bf16(afr[0][mf], b2, a, 0, 0, 0);
                a = __builtin_amdgcn_mfma_f32_16x16x32_bf16(afr[2][mf], b0, a, 0, 0, 0);
                acc[mf][nf] = a;
            }
        }
        __syncthreads();
    }

    // epilogue: C/D frag mapping col=lane&15, row=(lane>>4)*4+j  [m89-verified]
#pragma unroll
    for (int nf = 0; nf < 4; ++nf) {
        const int col = n0 + wn + nf * 16 + lr;
        const float bv = bias[col];
#pragma unroll
        for (int mf = 0; mf < 4; ++mf)
#pragma unroll
            for (int j = 0; j < 4; ++j) {
                const int row = m0 + wm + mf * 16 + lg * 4 + j;
                C[(size_t)row * Hsz + col] = acc[mf][nf][j] + bv;
            }
    }
}

// ===========================================================================
// Fallback fp32 GEMM (used only if d_ws is too small for the bf16x3 path)
// ===========================================================================
#define BM 128
#define BN 128
#define BK 16
#define LDSA (BM + 4)
#define LDSB (BN + 4)
__global__ __launch_bounds__(256) void sgemm_currents(
    const float* __restrict__ A, const float* __restrict__ B,
    const float* __restrict__ bias, float* __restrict__ C)
{
    __shared__ float As[BK][LDSA];
    __shared__ float Bs[BK][LDSB];
    const int tid = threadIdx.x;
    const int tx = tid & 15, ty = tid >> 4;
    const int m0 = blockIdx.y * BM, n0 = blockIdx.x * BN;
    const int arow = tid >> 2, ac4 = (tid & 3) * 4;
    const int brow = tid >> 5, bc4 = (tid & 31) * 4;
    float acc[8][8];
#pragma unroll
    for (int i = 0; i < 8; ++i)
#pragma unroll
        for (int j = 0; j < 8; ++j) acc[i][j] = 0.f;
    const float* Abase = A + (size_t)(m0 + arow) * Din + ac4;
    const float* Bbase = B + (size_t)brow * Hsz + n0 + bc4;
    float4 a0 = *(const float4*)Abase;
    float4 a1 = *(const float4*)(Abase + (size_t)64 * Din);
    float4 b0 = *(const float4*)Bbase;
    float4 b1 = *(const float4*)(Bbase + (size_t)8 * Hsz);
    const int NKT = Din / BK;
    for (int kt = 0; kt < NKT; ++kt) {
        const float* apf = (const float*)&a0;
        const float* aqf = (const float*)&a1;
#pragma unroll
        for (int j = 0; j < 4; ++j) As[ac4 + j][arow] = apf[j];
#pragma unroll
        for (int j = 0; j < 4; ++j) As[ac4 + j][arow + 64] = aqf[j];
        *(float4*)&Bs[brow][bc4] = b0;
        *(float4*)&Bs[brow + 8][bc4] = b1;
        __syncthreads();
        if (kt + 1 < NKT) {
            const float* An = Abase + (kt + 1) * BK;
            const float* Bn = Bbase + (size_t)(kt + 1) * BK * Hsz;
            a0 = *(const float4*)An;
            a1 = *(const float4*)(An + (size_t)64 * Din);
            b0 = *(const float4*)Bn;
            b1 = *(const float4*)(Bn + (size_t)8 * Hsz);
        }
#pragma unroll
        for (int k = 0; k < BK; ++k) {
            float4 af0 = *(const float4*)&As[k][ty * 8];
            float4 af1 = *(const float4*)&As[k][ty * 8 + 4];
            float4 bf0 = *(const float4*)&Bs[k][tx * 8];
            float4 bf1 = *(const float4*)&Bs[k][tx * 8 + 4];
            const float av[8] = {af0.x, af0.y, af0.z, af0.w, af1.x, af1.y, af1.z, af1.w};
            const float bv[8] = {bf0.x, bf0.y, bf0.z, bf0.w, bf1.x, bf1.y, bf1.z, bf1.w};
#pragma unroll
            for (int i = 0; i < 8; ++i)
#pragma unroll
                for (int j = 0; j < 8; ++j) acc[i][j] = fmaf(av[i], bv[j], acc[i][j]);
        }
        __syncthreads();
    }
    const float4 bi0 = *(const float4*)&bias[n0 + tx * 8];
    const float4 bi1 = *(const float4*)&bias[n0 + tx * 8 + 4];
#pragma unroll
    for (int i = 0; i < 8; ++i) {
        const size_t row = (size_t)(m0 + ty * 8 + i);
        float4 o0 = make_float4(acc[i][0] + bi0.x, acc[i][1] + bi0.y,
                                acc[i][2] + bi0.z, acc[i][3] + bi0.w);
        float4 o1 = make_float4(acc[i][4] + bi1.x, acc[i][5] + bi1.y,
                                acc[i][6] + bi1.z, acc[i][7] + bi1.w);
        float* cp = C + row * Hsz + n0 + tx * 8;
        *(float4*)cp = o0;
        *(float4*)(cp + 4) = o1;
    }
}

// ===========================================================================
// Pass 3: LIF scan. 256 blocks x 64 threads -> 1 wave on EVERY CU
// (was 64x256 = only 64 CUs active, per-CU-BW-bound).
// ===========================================================================
__global__ __launch_bounds__(64) void lif_scan(
    const float* cur, float* spikes, float* vmem, float* vfinal, float* partials)
{
    constexpr float A_M  = 0.95122942450071400910f;
    constexpr float OM_M = 1.0f - A_M;
    constexpr float A_S  = 0.81873075307798182354f;

    const int tid = threadIdx.x;
    const int gid = blockIdx.x * 64 + tid;            // 0..16383
    const size_t base = ((size_t)(gid >> 9)) * (size_t)Tsz * Hsz + (gid & 511);

    float v = 0.f, isyn = 0.f, acc = 0.f;
    constexpr int P = 8;
    float ring[P];
#pragma unroll
    for (int p = 0; p < P; ++p) ring[p] = cur[base + (size_t)p * Hsz];

    for (int t = 0; t < Tsz; t += P) {
#pragma unroll
        for (int p = 0; p < P; ++p) {
            const float c = ring[p];
            int tn = t + P + p;
            tn = tn < (Tsz - 1) ? tn : (Tsz - 1);
            ring[p] = cur[base + (size_t)tn * Hsz];

            isyn = fmaf(A_S, isyn, c);
            v    = fmaf(A_M, v, OM_M * isyn);
            const float sp = (v >= 1.0f) ? 1.0f : 0.0f;
            const float x  = 4.0f * (v - 1.0f);
            const float surr = 4.0f / (2.0f + __expf(x) + __expf(-x));
            const float so   = fmaf(2.0f, sp, -surr);
            v = (sp > 0.f) ? 0.0f : v;

            const size_t idx = base + (size_t)(t + p) * Hsz;
            spikes[idx] = so;
            vmem[idx]   = v;
            acc += so;
        }
    }
    vfinal[gid] = v;
#pragma unroll
    for (int off = 32; off; off >>= 1) acc += __shfl_down(acc, off);
    if (tid == 0) partials[blockIdx.x] = acc;
}

__global__ __launch_bounds__(256) void rate_finalize(
    const float* __restrict__ partials, float* __restrict__ rate)
{
    const int tid = threadIdx.x;
    float s = partials[tid];
#pragma unroll
    for (int off = 32; off; off >>= 1) s += __shfl_down(s, off);
    __shared__ float wsum[4];
    if ((tid & 63) == 0) wsum[tid >> 6] = s;
    __syncthreads();
    if (tid == 0)
        rate[0] = ((wsum[0] + wsum[1]) + (wsum[2] + wsum[3])) * (1.0f / 16777216.0f);
}

// ===========================================================================
extern "C" void kernel_launch(void* const* d_in, const int* in_sizes, int n_in,
                              void* d_out, int out_size, void* d_ws, size_t ws_size,
                              hipStream_t stream)
{
    const float* inputs = (const float*)d_in[0];
    const float* weight = (const float*)d_in[1];
    const float* bias   = (const float*)d_in[2];

    float* out    = (float*)d_out;
    float* spikes = out;
    float* vmem   = out + ELEMS;
    float* vfinal = out + 2 * ELEMS;
    float* rate   = vfinal + (size_t)Bsz * Hsz;

    float* partials = (float*)d_ws;                  // 256 floats
    char*  ws       = (char*)d_ws;

    const size_t CUR_B = ELEMS * 4;                  // 64 MiB
    const size_t ALV_B = 3 * ELEMS * 2;              // 96 MiB  (3 bf16 limbs of A)
    const size_t BLV_B = 3 * (size_t)Din * Hsz * 2;  // 1.5 MiB (3 bf16 limbs of W^T)

    ushort_t *A0, *A1, *A2, *B0, *B1, *B2;
    float* cur;
    int path;                                        // 0 = all-in-ws, 1 = limbs-in-out, 2 = fp32 fallback
    if (ws_size >= 4096 + CUR_B + ALV_B + BLV_B) {
        cur = (float*)(ws + 4096);
        A0 = (ushort_t*)(ws + 4096 + CUR_B); A1 = A0 + ELEMS; A2 = A1 + ELEMS;
        B0 = A2 + ELEMS; B1 = B0 + (size_t)Din * Hsz; B2 = B1 + (size_t)Din * Hsz;
        path = 0;
    } else if (ws_size >= 4096 + CUR_B) {
        cur = (float*)(ws + 4096);
        A0 = (ushort_t*)d_out; A1 = A0 + ELEMS; A2 = A1 + ELEMS;   // 96 MiB of 128 MiB out
        B0 = A2 + ELEMS; B1 = B0 + (size_t)Din * Hsz; B2 = B1 + (size_t)Din * Hsz;
        path = 1;                                    // scan overwrites limbs afterwards
    } else {
        cur = vmem;                                  // read-before-overwrite in scan
        A0 = A1 = A2 = B0 = B1 = B2 = nullptr;
        path = 2;
    }

    if (path != 2) {
        split_bf16x3<<<dim3(4096 + 256), 256, 0, stream>>>(inputs, weight,
                                                           A0, A1, A2, B0, B1, B2);
        gemm_bf16x3<<<dim3(4, 256), 256, 0, stream>>>(A0, A1, A2, B0, B1, B2, bias, cur);
    } else {
        sgemm_currents<<<dim3(4, 256), 256, 0, stream>>>(inputs, weight, bias, cur);
    }
    lif_scan<<<dim3(256), 64, 0, stream>>>(cur, spikes, vmem, vfinal, partials);
    rate_finalize<<<dim3(1), 256, 0, stream>>>(partials, rate);
}

// Round 3
// 263.992 us; speedup vs baseline: 1.8003x; 1.8003x over previous
//
#include <hip/hip_runtime.h>

typedef unsigned short ushort_t;
typedef unsigned int   uint_t;
typedef float  float4v __attribute__((ext_vector_type(4)));
typedef __bf16 bf16x8  __attribute__((ext_vector_type(8)));

#define Bsz 32
#define Tsz 1024
#define Din 512
#define Hsz 512
#define Mtot (Bsz * Tsz)                 // 32768
#define ELEMS ((size_t)Mtot * Hsz)       // 16777216
#define BELEM ((size_t)Din * Hsz)        // 262144 per B limb

#define GLL16(gp, lp) __builtin_amdgcn_global_load_lds(                        \
    (const __attribute__((address_space(1))) unsigned int*)(gp),               \
    (__attribute__((address_space(3))) unsigned int*)(lp), 16, 0, 0)

// ===========================================================================
// Pass 1: exact 3-way bf16 truncation split (x == h0+h1+h2 bitwise).
//   A [Mtot,Din] fp32 -> A0,A1,A2 bf16 (same layout)
//   W [Din,Hsz] fp32  -> B0,B1,B2 bf16 TRANSPOSED [Hsz][Din]
// ===========================================================================
__device__ __forceinline__ void split3(float c, uint_t& h0, uint_t& h1, uint_t& h2)
{
    uint_t t0 = __float_as_uint(c) & 0xFFFF0000u;
    float  r1 = c - __uint_as_float(t0);
    uint_t t1 = __float_as_uint(r1) & 0xFFFF0000u;
    float  r2 = r1 - __uint_as_float(t1);
    uint_t t2 = __float_as_uint(r2) & 0xFFFF0000u;
    h0 = t0 >> 16; h1 = t1 >> 16; h2 = t2 >> 16;
}

__global__ __launch_bounds__(256) void split_bf16x3(
    const float* __restrict__ A, const float* __restrict__ W,
    ushort_t* __restrict__ A0, ushort_t* __restrict__ A1, ushort_t* __restrict__ A2,
    ushort_t* __restrict__ B0, ushort_t* __restrict__ B1, ushort_t* __restrict__ B2)
{
    const int bid = blockIdx.x, tid = threadIdx.x;
    if (bid < 4096) {                       // A split
        const float4* Af = (const float4*)A;
#pragma unroll
        for (int q = 0; q < 4; ++q) {
            const size_t i = (size_t)bid * 1024 + q * 256 + tid;
            float4 x = Af[i];
            const float c[4] = {x.x, x.y, x.z, x.w};
            uint_t h0[4], h1[4], h2[4];
#pragma unroll
            for (int j = 0; j < 4; ++j) split3(c[j], h0[j], h1[j], h2[j]);
            *(uint2*)(A0 + 4 * i) = make_uint2(h0[0] | (h0[1] << 16), h0[2] | (h0[3] << 16));
            *(uint2*)(A1 + 4 * i) = make_uint2(h1[0] | (h1[1] << 16), h1[2] | (h1[3] << 16));
            *(uint2*)(A2 + 4 * i) = make_uint2(h2[0] | (h2[1] << 16), h2[2] | (h2[3] << 16));
        }
    } else {                                // W split + transpose (1.5 MiB, cheap)
        const int f4 = (bid - 4096) * 256 + tid;
        const int k  = f4 >> 7;
        const int n4 = (f4 & 127) << 2;
        float4 x = *(const float4*)(W + (size_t)k * Hsz + n4);
        const float c[4] = {x.x, x.y, x.z, x.w};
#pragma unroll
        for (int j = 0; j < 4; ++j) {
            uint_t h0, h1, h2;
            split3(c[j], h0, h1, h2);
            const size_t o = (size_t)(n4 + j) * Din + k;
            B0[o] = (ushort_t)h0; B1[o] = (ushort_t)h1; B2[o] = (ushort_t)h2;
        }
    }
}

// ===========================================================================
// Pass 2: bf16x3 MFMA GEMM, virtual K = 6 pairs x 512.
// m97 structure: 128x128 tile, 4 waves, BK=64, global_load_lds dwordx4,
// double-buffered LDS, chunk-XOR swizzle (linear LDS dest + pre-swizzled
// global source + matching swizzled ds_read -> conflict-free b128).
// Pair order (A-limb grouped): (A0,B0)(A0,B1)(A0,B2)(A1,B0)(A1,B1)(A2,B0).
// ===========================================================================
__global__ __launch_bounds__(256, 2) void gemm_limb(
    const ushort_t* __restrict__ A0, const ushort_t* __restrict__ A1,
    const ushort_t* __restrict__ A2,
    const ushort_t* __restrict__ B0, const ushort_t* __restrict__ B1,
    const ushort_t* __restrict__ B2,
    const float* __restrict__ bias, float* __restrict__ C)
{
    __shared__ __align__(16) ushort_t As[2][128 * 64];   // 16 KiB each
    __shared__ __align__(16) ushort_t Bs[2][128 * 64];

    const int tid  = threadIdx.x;
    // XCD-aware swizzle (nwg=1024, %8==0 -> bijective)
    const int lin  = ((blockIdx.x & 7) << 7) | (blockIdx.x >> 3);
    const int m0   = (lin >> 2) << 7;        // 256 m-panels
    const int n0   = (lin & 3) << 7;         // 4 n-panels
    const int wave = tid >> 6, lane = tid & 63;
    const int wm = (wave & 1) << 6, wn = (wave >> 1) << 6;
    const int lr = lane & 15, lg = lane >> 4;

    // staging per-thread constants: thread -> (row = tid>>3 within 32-row
    // segment, physical 16B chunk = tid&7). Source fetches logical chunk
    // (tid&7)^(row&7) so LDS physical chunk p holds logical p^(row&7).
    const int arow = tid >> 3;
    const int achk = (tid & 7) ^ (arow & 7);
    const size_t aoff = (size_t)(m0 + arow) * 1024 + (size_t)(achk * 16); // bytes
    const size_t boff = (size_t)(n0 + arow) * 1024 + (size_t)(achk * 16);

    float4v acc[4][4];
#pragma unroll
    for (int i = 0; i < 4; ++i)
#pragma unroll
        for (int j = 0; j < 4; ++j) acc[i][j] = (float4v)0.f;

    {   // prologue: chunk 0 = pair (A0,B0), k=0
        const char* ga = (const char*)A0 + aoff;
        const char* gb = (const char*)B0 + boff;
        char* la = (char*)(&As[0][0]) + tid * 16;
        char* lb = (char*)(&Bs[0][0]) + tid * 16;
#pragma unroll
        for (int r = 0; r < 4; ++r) {
            GLL16(ga + r * 32768, la + r * 4096);   // 32 rows * 1024 B
            GLL16(gb + r * 32768, lb + r * 4096);
        }
    }
    __syncthreads();

    int buf = 0;
    for (int c = 0; c < 48; ++c) {
        if (c + 1 < 48) {           // prefetch next chunk into other buffer
            const int cn = c + 1;
            const int p  = cn >> 3;
            const ushort_t* ap = (p < 3) ? A0 : ((p < 5) ? A1 : A2);
            const int bq       = (p < 3) ? p : ((p < 5) ? (p - 3) : 0);
            const ushort_t* bp = (bq == 0) ? B0 : ((bq == 1) ? B1 : B2);
            const int kbyte = (cn & 7) << 7;        // 64 bf16 = 128 B per chunk
            const char* ga = (const char*)ap + aoff + kbyte;
            const char* gb = (const char*)bp + boff + kbyte;
            char* la = (char*)(&As[buf ^ 1][0]) + tid * 16;
            char* lb = (char*)(&Bs[buf ^ 1][0]) + tid * 16;
#pragma unroll
            for (int r = 0; r < 4; ++r) {
                GLL16(ga + r * 32768, la + r * 4096);
                GLL16(gb + r * 32768, lb + r * 4096);
            }
        }

        const char* asb = (const char*)(&As[buf][0]);
        const char* bsb = (const char*)(&Bs[buf][0]);
#pragma unroll
        for (int kk = 0; kk < 2; ++kk) {
            bf16x8 af[4], bf[4];
#pragma unroll
            for (int mf = 0; mf < 4; ++mf) {
                const int row  = wm + mf * 16 + lr;
                const int phys = ((kk << 2) | lg) ^ (lr & 7);
                af[mf] = *(const bf16x8*)(asb + row * 128 + phys * 16);
            }
#pragma unroll
            for (int nf = 0; nf < 4; ++nf) {
                const int row  = wn + nf * 16 + lr;
                const int phys = ((kk << 2) | lg) ^ (lr & 7);
                bf[nf] = *(const bf16x8*)(bsb + row * 128 + phys * 16);
            }
#pragma unroll
            for (int nf = 0; nf < 4; ++nf)
#pragma unroll
                for (int mf = 0; mf < 4; ++mf)
                    acc[mf][nf] = __builtin_amdgcn_mfma_f32_16x16x32_bf16(
                        af[mf], bf[nf], acc[mf][nf], 0, 0, 0);
        }
        __syncthreads();
        buf ^= 1;
    }

    // epilogue (C/D map verified by round-2 pass): col=lr side, row=lg*4+j
#pragma unroll
    for (int nf = 0; nf < 4; ++nf) {
        const int col = n0 + wn + nf * 16 + lr;
        const float bv = bias[col];
#pragma unroll
        for (int mf = 0; mf < 4; ++mf)
#pragma unroll
            for (int j = 0; j < 4; ++j) {
                const int row = m0 + wm + mf * 16 + lg * 4 + j;
                C[(size_t)row * Hsz + col] = acc[mf][nf][j] + bv;
            }
    }
}

// ===========================================================================
// Fallback fp32 GEMM (only if d_ws too small for bf16x3 path)
// ===========================================================================
#define BM 128
#define BN 128
#define BK 16
#define LDSA (BM + 4)
#define LDSB (BN + 4)
__global__ __launch_bounds__(256) void sgemm_currents(
    const float* __restrict__ A, const float* __restrict__ B,
    const float* __restrict__ bias, float* __restrict__ C)
{
    __shared__ float As[BK][LDSA];
    __shared__ float Bs[BK][LDSB];
    const int tid = threadIdx.x;
    const int tx = tid & 15, ty = tid >> 4;
    const int m0 = blockIdx.y * BM, n0 = blockIdx.x * BN;
    const int arow = tid >> 2, ac4 = (tid & 3) * 4;
    const int brow = tid >> 5, bc4 = (tid & 31) * 4;
    float acc[8][8];
#pragma unroll
    for (int i = 0; i < 8; ++i)
#pragma unroll
        for (int j = 0; j < 8; ++j) acc[i][j] = 0.f;
    const float* Abase = A + (size_t)(m0 + arow) * Din + ac4;
    const float* Bbase = B + (size_t)brow * Hsz + n0 + bc4;
    float4 a0 = *(const float4*)Abase;
    float4 a1 = *(const float4*)(Abase + (size_t)64 * Din);
    float4 b0 = *(const float4*)Bbase;
    float4 b1 = *(const float4*)(Bbase + (size_t)8 * Hsz);
    const int NKT = Din / BK;
    for (int kt = 0; kt < NKT; ++kt) {
        const float* apf = (const float*)&a0;
        const float* aqf = (const float*)&a1;
#pragma unroll
        for (int j = 0; j < 4; ++j) As[ac4 + j][arow] = apf[j];
#pragma unroll
        for (int j = 0; j < 4; ++j) As[ac4 + j][arow + 64] = aqf[j];
        *(float4*)&Bs[brow][bc4] = b0;
        *(float4*)&Bs[brow + 8][bc4] = b1;
        __syncthreads();
        if (kt + 1 < NKT) {
            const float* An = Abase + (kt + 1) * BK;
            const float* Bn = Bbase + (size_t)(kt + 1) * BK * Hsz;
            a0 = *(const float4*)An;
            a1 = *(const float4*)(An + (size_t)64 * Din);
            b0 = *(const float4*)Bn;
            b1 = *(const float4*)(Bn + (size_t)8 * Hsz);
        }
#pragma unroll
        for (int k = 0; k < BK; ++k) {
            float4 af0 = *(const float4*)&As[k][ty * 8];
            float4 af1 = *(const float4*)&As[k][ty * 8 + 4];
            float4 bf0 = *(const float4*)&Bs[k][tx * 8];
            float4 bf1 = *(const float4*)&Bs[k][tx * 8 + 4];
            const float av[8] = {af0.x, af0.y, af0.z, af0.w, af1.x, af1.y, af1.z, af1.w};
            const float bv[8] = {bf0.x, bf0.y, bf0.z, bf0.w, bf1.x, bf1.y, bf1.z, bf1.w};
#pragma unroll
            for (int i = 0; i < 8; ++i)
#pragma unroll
                for (int j = 0; j < 8; ++j) acc[i][j] = fmaf(av[i], bv[j], acc[i][j]);
        }
        __syncthreads();
    }
    const float4 bi0 = *(const float4*)&bias[n0 + tx * 8];
    const float4 bi1 = *(const float4*)&bias[n0 + tx * 8 + 4];
#pragma unroll
    for (int i = 0; i < 8; ++i) {
        const size_t row = (size_t)(m0 + ty * 8 + i);
        float4 o0 = make_float4(acc[i][0] + bi0.x, acc[i][1] + bi0.y,
                                acc[i][2] + bi0.z, acc[i][3] + bi0.w);
        float4 o1 = make_float4(acc[i][4] + bi1.x, acc[i][5] + bi1.y,
                                acc[i][6] + bi1.z, acc[i][7] + bi1.w);
        float* cp = C + row * Hsz + n0 + tx * 8;
        *(float4*)cp = o0;
        *(float4*)(cp + 4) = o1;
    }
}

// ===========================================================================
// Pass 3: LIF scan. 256 blocks x 64 threads -> 1 wave on every CU.
// ===========================================================================
__global__ __launch_bounds__(64) void lif_scan(
    const float* cur, float* spikes, float* vmem, float* vfinal, float* partials)
{
    constexpr float A_M  = 0.95122942450071400910f;
    constexpr float OM_M = 1.0f - A_M;
    constexpr float A_S  = 0.81873075307798182354f;

    const int tid = threadIdx.x;
    const int gid = blockIdx.x * 64 + tid;
    const size_t base = ((size_t)(gid >> 9)) * (size_t)Tsz * Hsz + (gid & 511);

    float v = 0.f, isyn = 0.f, acc = 0.f;
    constexpr int P = 8;
    float ring[P];
#pragma unroll
    for (int p = 0; p < P; ++p) ring[p] = cur[base + (size_t)p * Hsz];

    for (int t = 0; t < Tsz; t += P) {
#pragma unroll
        for (int p = 0; p < P; ++p) {
            const float c = ring[p];
            int tn = t + P + p;
            tn = tn < (Tsz - 1) ? tn : (Tsz - 1);
            ring[p] = cur[base + (size_t)tn * Hsz];

            isyn = fmaf(A_S, isyn, c);
            v    = fmaf(A_M, v, OM_M * isyn);
            const float sp = (v >= 1.0f) ? 1.0f : 0.0f;
            const float x  = 4.0f * (v - 1.0f);
            const float surr = 4.0f / (2.0f + __expf(x) + __expf(-x));
            const float so   = fmaf(2.0f, sp, -surr);
            v = (sp > 0.f) ? 0.0f : v;

            const size_t idx = base + (size_t)(t + p) * Hsz;
            spikes[idx] = so;
            vmem[idx]   = v;
            acc += so;
        }
    }
    vfinal[gid] = v;
#pragma unroll
    for (int off = 32; off; off >>= 1) acc += __shfl_down(acc, off);
    if (tid == 0) partials[blockIdx.x] = acc;
}

__global__ __launch_bounds__(256) void rate_finalize(
    const float* __restrict__ partials, float* __restrict__ rate)
{
    const int tid = threadIdx.x;
    float s = partials[tid];
#pragma unroll
    for (int off = 32; off; off >>= 1) s += __shfl_down(s, off);
    __shared__ float wsum[4];
    if ((tid & 63) == 0) wsum[tid >> 6] = s;
    __syncthreads();
    if (tid == 0)
        rate[0] = ((wsum[0] + wsum[1]) + (wsum[2] + wsum[3])) * (1.0f / 16777216.0f);
}

// ===========================================================================
extern "C" void kernel_launch(void* const* d_in, const int* in_sizes, int n_in,
                              void* d_out, int out_size, void* d_ws, size_t ws_size,
                              hipStream_t stream)
{
    const float* inputs = (const float*)d_in[0];
    const float* weight = (const float*)d_in[1];
    const float* bias   = (const float*)d_in[2];

    float* out    = (float*)d_out;
    float* spikes = out;
    float* vmem   = out + ELEMS;
    float* vfinal = out + 2 * ELEMS;
    float* rate   = vfinal + (size_t)Bsz * Hsz;

    float* partials = (float*)d_ws;
    char*  ws       = (char*)d_ws;

    const size_t CUR_B = ELEMS * 4;          // 64 MiB
    const size_t ALV_B = 3 * ELEMS * 2;      // 96 MiB
    const size_t BLV_B = 3 * BELEM * 2;      // 1.5 MiB

    ushort_t *A0, *A1, *A2, *B0, *B1, *B2;
    float* cur;
    int path;
    if (ws_size >= 4096 + CUR_B + ALV_B + BLV_B) {
        cur = (float*)(ws + 4096);
        A0 = (ushort_t*)(ws + 4096 + CUR_B); A1 = A0 + ELEMS; A2 = A1 + ELEMS;
        B0 = A2 + ELEMS; B1 = B0 + BELEM; B2 = B1 + BELEM;
        path = 0;
    } else if (ws_size >= 4096 + CUR_B) {
        cur = (float*)(ws + 4096);
        A0 = (ushort_t*)d_out; A1 = A0 + ELEMS; A2 = A1 + ELEMS;  // scan overwrites later
        B0 = A2 + ELEMS; B1 = B0 + BELEM; B2 = B1 + BELEM;
        path = 1;
    } else {
        cur = vmem;
        A0 = A1 = A2 = B0 = B1 = B2 = nullptr;
        path = 2;
    }

    if (path != 2) {
        split_bf16x3<<<dim3(4096 + 256), 256, 0, stream>>>(inputs, weight,
                                                           A0, A1, A2, B0, B1, B2);
        gemm_limb<<<dim3(1024), 256, 0, stream>>>(A0, A1, A2, B0, B1, B2, bias, cur);
    } else {
        sgemm_currents<<<dim3(4, 256), 256, 0, stream>>>(inputs, weight, bias, cur);
    }
    lif_scan<<<dim3(256), 64, 0, stream>>>(cur, spikes, vmem, vfinal, partials);
    rate_finalize<<<dim3(1), 256, 0, stream>>>(partials, rate);
}

// Round 4
// 235.170 us; speedup vs baseline: 2.0210x; 1.1226x over previous
//
#include <hip/hip_runtime.h>

typedef unsigned short ushort_t;
typedef unsigned int   uint_t;
typedef float  float4v __attribute__((ext_vector_type(4)));
typedef __bf16 bf16x8  __attribute__((ext_vector_type(8)));

#define Bsz 32
#define Tsz 1024
#define Din 512
#define Hsz 512
#define Mtot (Bsz * Tsz)                 // 32768
#define ELEMS ((size_t)Mtot * Hsz)       // 16777216
#define BELEM ((size_t)Din * Hsz)        // 262144 per B limb

#define GLL16(gp, lp) __builtin_amdgcn_global_load_lds(                        \
    (const __attribute__((address_space(1))) unsigned int*)(gp),               \
    (__attribute__((address_space(3))) unsigned int*)(lp), 16, 0, 0)

// ===========================================================================
// Pass 1: exact 3-way bf16 truncation split (x == h0+h1+h2 bitwise).
// ===========================================================================
__device__ __forceinline__ void split3(float c, uint_t& h0, uint_t& h1, uint_t& h2)
{
    uint_t t0 = __float_as_uint(c) & 0xFFFF0000u;
    float  r1 = c - __uint_as_float(t0);
    uint_t t1 = __float_as_uint(r1) & 0xFFFF0000u;
    float  r2 = r1 - __uint_as_float(t1);
    uint_t t2 = __float_as_uint(r2) & 0xFFFF0000u;
    h0 = t0 >> 16; h1 = t1 >> 16; h2 = t2 >> 16;
}

__global__ __launch_bounds__(256) void split_bf16x3(
    const float* __restrict__ A, const float* __restrict__ W,
    ushort_t* __restrict__ A0, ushort_t* __restrict__ A1, ushort_t* __restrict__ A2,
    ushort_t* __restrict__ B0, ushort_t* __restrict__ B1, ushort_t* __restrict__ B2)
{
    const int bid = blockIdx.x, tid = threadIdx.x;
    if (bid < 4096) {                       // A split
        const float4* Af = (const float4*)A;
#pragma unroll
        for (int q = 0; q < 4; ++q) {
            const size_t i = (size_t)bid * 1024 + q * 256 + tid;
            float4 x = Af[i];
            const float c[4] = {x.x, x.y, x.z, x.w};
            uint_t h0[4], h1[4], h2[4];
#pragma unroll
            for (int j = 0; j < 4; ++j) split3(c[j], h0[j], h1[j], h2[j]);
            *(uint2*)(A0 + 4 * i) = make_uint2(h0[0] | (h0[1] << 16), h0[2] | (h0[3] << 16));
            *(uint2*)(A1 + 4 * i) = make_uint2(h1[0] | (h1[1] << 16), h1[2] | (h1[3] << 16));
            *(uint2*)(A2 + 4 * i) = make_uint2(h2[0] | (h2[1] << 16), h2[2] | (h2[3] << 16));
        }
    } else {                                // W split + transpose (1.5 MiB, cheap)
        const int f4 = (bid - 4096) * 256 + tid;
        const int k  = f4 >> 7;
        const int n4 = (f4 & 127) << 2;
        float4 x = *(const float4*)(W + (size_t)k * Hsz + n4);
        const float c[4] = {x.x, x.y, x.z, x.w};
#pragma unroll
        for (int j = 0; j < 4; ++j) {
            uint_t h0, h1, h2;
            split3(c[j], h0, h1, h2);
            const size_t o = (size_t)(n4 + j) * Din + k;
            B0[o] = (ushort_t)h0; B1[o] = (ushort_t)h1; B2[o] = (ushort_t)h2;
        }
    }
}

// ===========================================================================
// Pass 2: bf16x3 MFMA GEMM, virtual K = 6 pairs x 512 (unchanged from R3:
// 124 us, at the m97-structure ceiling; 8-phase port is the next step).
// ===========================================================================
__global__ __launch_bounds__(256, 2) void gemm_limb(
    const ushort_t* __restrict__ A0, const ushort_t* __restrict__ A1,
    const ushort_t* __restrict__ A2,
    const ushort_t* __restrict__ B0, const ushort_t* __restrict__ B1,
    const ushort_t* __restrict__ B2,
    const float* __restrict__ bias, float* __restrict__ C)
{
    __shared__ __align__(16) ushort_t As[2][128 * 64];
    __shared__ __align__(16) ushort_t Bs[2][128 * 64];

    const int tid  = threadIdx.x;
    const int lin  = ((blockIdx.x & 7) << 7) | (blockIdx.x >> 3);
    const int m0   = (lin >> 2) << 7;
    const int n0   = (lin & 3) << 7;
    const int wave = tid >> 6, lane = tid & 63;
    const int wm = (wave & 1) << 6, wn = (wave >> 1) << 6;
    const int lr = lane & 15, lg = lane >> 4;

    const int arow = tid >> 3;
    const int achk = (tid & 7) ^ (arow & 7);
    const size_t aoff = (size_t)(m0 + arow) * 1024 + (size_t)(achk * 16);
    const size_t boff = (size_t)(n0 + arow) * 1024 + (size_t)(achk * 16);

    float4v acc[4][4];
#pragma unroll
    for (int i = 0; i < 4; ++i)
#pragma unroll
        for (int j = 0; j < 4; ++j) acc[i][j] = (float4v)0.f;

    {
        const char* ga = (const char*)A0 + aoff;
        const char* gb = (const char*)B0 + boff;
        char* la = (char*)(&As[0][0]) + tid * 16;
        char* lb = (char*)(&Bs[0][0]) + tid * 16;
#pragma unroll
        for (int r = 0; r < 4; ++r) {
            GLL16(ga + r * 32768, la + r * 4096);
            GLL16(gb + r * 32768, lb + r * 4096);
        }
    }
    __syncthreads();

    int buf = 0;
    for (int c = 0; c < 48; ++c) {
        if (c + 1 < 48) {
            const int cn = c + 1;
            const int p  = cn >> 3;
            const ushort_t* ap = (p < 3) ? A0 : ((p < 5) ? A1 : A2);
            const int bq       = (p < 3) ? p : ((p < 5) ? (p - 3) : 0);
            const ushort_t* bp = (bq == 0) ? B0 : ((bq == 1) ? B1 : B2);
            const int kbyte = (cn & 7) << 7;
            const char* ga = (const char*)ap + aoff + kbyte;
            const char* gb = (const char*)bp + boff + kbyte;
            char* la = (char*)(&As[buf ^ 1][0]) + tid * 16;
            char* lb = (char*)(&Bs[buf ^ 1][0]) + tid * 16;
#pragma unroll
            for (int r = 0; r < 4; ++r) {
                GLL16(ga + r * 32768, la + r * 4096);
                GLL16(gb + r * 32768, lb + r * 4096);
            }
        }

        const char* asb = (const char*)(&As[buf][0]);
        const char* bsb = (const char*)(&Bs[buf][0]);
#pragma unroll
        for (int kk = 0; kk < 2; ++kk) {
            bf16x8 af[4], bf[4];
#pragma unroll
            for (int mf = 0; mf < 4; ++mf) {
                const int row  = wm + mf * 16 + lr;
                const int phys = ((kk << 2) | lg) ^ (lr & 7);
                af[mf] = *(const bf16x8*)(asb + row * 128 + phys * 16);
            }
#pragma unroll
            for (int nf = 0; nf < 4; ++nf) {
                const int row  = wn + nf * 16 + lr;
                const int phys = ((kk << 2) | lg) ^ (lr & 7);
                bf[nf] = *(const bf16x8*)(bsb + row * 128 + phys * 16);
            }
#pragma unroll
            for (int nf = 0; nf < 4; ++nf)
#pragma unroll
                for (int mf = 0; mf < 4; ++mf)
                    acc[mf][nf] = __builtin_amdgcn_mfma_f32_16x16x32_bf16(
                        af[mf], bf[nf], acc[mf][nf], 0, 0, 0);
        }
        __syncthreads();
        buf ^= 1;
    }

#pragma unroll
    for (int nf = 0; nf < 4; ++nf) {
        const int col = n0 + wn + nf * 16 + lr;
        const float bv = bias[col];
#pragma unroll
        for (int mf = 0; mf < 4; ++mf)
#pragma unroll
            for (int j = 0; j < 4; ++j) {
                const int row = m0 + wm + mf * 16 + lg * 4 + j;
                C[(size_t)row * Hsz + col] = acc[mf][nf][j] + bv;
            }
    }
}

// ===========================================================================
// Fallback fp32 GEMM (only if d_ws too small for bf16x3 path)
// ===========================================================================
#define BM 128
#define BN 128
#define BK 16
#define LDSA (BM + 4)
#define LDSB (BN + 4)
__global__ __launch_bounds__(256) void sgemm_currents(
    const float* __restrict__ A, const float* __restrict__ B,
    const float* __restrict__ bias, float* __restrict__ C)
{
    __shared__ float As[BK][LDSA];
    __shared__ float Bs[BK][LDSB];
    const int tid = threadIdx.x;
    const int tx = tid & 15, ty = tid >> 4;
    const int m0 = blockIdx.y * BM, n0 = blockIdx.x * BN;
    const int arow = tid >> 2, ac4 = (tid & 3) * 4;
    const int brow = tid >> 5, bc4 = (tid & 31) * 4;
    float acc[8][8];
#pragma unroll
    for (int i = 0; i < 8; ++i)
#pragma unroll
        for (int j = 0; j < 8; ++j) acc[i][j] = 0.f;
    const float* Abase = A + (size_t)(m0 + arow) * Din + ac4;
    const float* Bbase = B + (size_t)brow * Hsz + n0 + bc4;
    float4 a0 = *(const float4*)Abase;
    float4 a1 = *(const float4*)(Abase + (size_t)64 * Din);
    float4 b0 = *(const float4*)Bbase;
    float4 b1 = *(const float4*)(Bbase + (size_t)8 * Hsz);
    const int NKT = Din / BK;
    for (int kt = 0; kt < NKT; ++kt) {
        const float* apf = (const float*)&a0;
        const float* aqf = (const float*)&a1;
#pragma unroll
        for (int j = 0; j < 4; ++j) As[ac4 + j][arow] = apf[j];
#pragma unroll
        for (int j = 0; j < 4; ++j) As[ac4 + j][arow + 64] = aqf[j];
        *(float4*)&Bs[brow][bc4] = b0;
        *(float4*)&Bs[brow + 8][bc4] = b1;
        __syncthreads();
        if (kt + 1 < NKT) {
            const float* An = Abase + (kt + 1) * BK;
            const float* Bn = Bbase + (size_t)(kt + 1) * BK * Hsz;
            a0 = *(const float4*)An;
            a1 = *(const float4*)(An + (size_t)64 * Din);
            b0 = *(const float4*)Bn;
            b1 = *(const float4*)(Bn + (size_t)8 * Hsz);
        }
#pragma unroll
        for (int k = 0; k < BK; ++k) {
            float4 af0 = *(const float4*)&As[k][ty * 8];
            float4 af1 = *(const float4*)&As[k][ty * 8 + 4];
            float4 bf0 = *(const float4*)&Bs[k][tx * 8];
            float4 bf1 = *(const float4*)&Bs[k][tx * 8 + 4];
            const float av[8] = {af0.x, af0.y, af0.z, af0.w, af1.x, af1.y, af1.z, af1.w};
            const float bv[8] = {bf0.x, bf0.y, bf0.z, bf0.w, bf1.x, bf1.y, bf1.z, bf1.w};
#pragma unroll
            for (int i = 0; i < 8; ++i)
#pragma unroll
                for (int j = 0; j < 8; ++j) acc[i][j] = fmaf(av[i], bv[j], acc[i][j]);
        }
        __syncthreads();
    }
    const float4 bi0 = *(const float4*)&bias[n0 + tx * 8];
    const float4 bi1 = *(const float4*)&bias[n0 + tx * 8 + 4];
#pragma unroll
    for (int i = 0; i < 8; ++i) {
        const size_t row = (size_t)(m0 + ty * 8 + i);
        float4 o0 = make_float4(acc[i][0] + bi0.x, acc[i][1] + bi0.y,
                                acc[i][2] + bi0.z, acc[i][3] + bi0.w);
        float4 o1 = make_float4(acc[i][4] + bi1.x, acc[i][5] + bi1.y,
                                acc[i][6] + bi1.z, acc[i][7] + bi1.w);
        float* cp = C + row * Hsz + n0 + tx * 8;
        *(float4*)cp = o0;
        *(float4*)(cp + 4) = o1;
    }
}

// ===========================================================================
// Pass 3a: LIF scan, NON-ALIASED path (cur disjoint from outputs).
// __restrict__ lets the ring prefetch actually stay in flight (no
// load-after-store waits); P=32 outstanding loads/wave covers ~900cy HBM
// latency at 1 wave/CU; nontemporal stores keep the 128 MiB output stream
// from evicting the L3-resident currents.
// ===========================================================================
__global__ __launch_bounds__(64) void lif_scan_r(
    const float* __restrict__ cur, float* __restrict__ spikes,
    float* __restrict__ vmem, float* __restrict__ vfinal,
    float* __restrict__ partials)
{
    constexpr float A_M  = 0.95122942450071400910f;
    constexpr float OM_M = 1.0f - A_M;
    constexpr float A_S  = 0.81873075307798182354f;

    const int tid = threadIdx.x;
    const int gid = blockIdx.x * 64 + tid;
    const size_t base = ((size_t)(gid >> 9)) * (size_t)Tsz * Hsz + (gid & 511);

    float v = 0.f, isyn = 0.f, acc = 0.f;
    constexpr int P = 32;
    float ring[P];
#pragma unroll
    for (int p = 0; p < P; ++p) ring[p] = cur[base + (size_t)p * Hsz];

    for (int t = 0; t < Tsz; t += P) {
#pragma unroll
        for (int p = 0; p < P; ++p) {
            const float c = ring[p];
            int tn = t + P + p;
            tn = tn < (Tsz - 1) ? tn : (Tsz - 1);
            ring[p] = cur[base + (size_t)tn * Hsz];

            isyn = fmaf(A_S, isyn, c);
            v    = fmaf(A_M, v, OM_M * isyn);
            const float sp = (v >= 1.0f) ? 1.0f : 0.0f;
            const float x  = 4.0f * (v - 1.0f);
            const float surr = 4.0f / (2.0f + __expf(x) + __expf(-x));
            const float so   = fmaf(2.0f, sp, -surr);
            v = (sp > 0.f) ? 0.0f : v;

            const size_t idx = base + (size_t)(t + p) * Hsz;
            __builtin_nontemporal_store(so, &spikes[idx]);
            __builtin_nontemporal_store(v,  &vmem[idx]);
            acc += so;
        }
    }
    vfinal[gid] = v;
#pragma unroll
    for (int off = 32; off; off >>= 1) acc += __shfl_down(acc, off);
    if (tid == 0) partials[blockIdx.x] = acc;
}

// ===========================================================================
// Pass 3b: LIF scan, ALIAS-SAFE fallback (cur may be the vmem region).
// ===========================================================================
__global__ __launch_bounds__(64) void lif_scan(
    const float* cur, float* spikes, float* vmem, float* vfinal, float* partials)
{
    constexpr float A_M  = 0.95122942450071400910f;
    constexpr float OM_M = 1.0f - A_M;
    constexpr float A_S  = 0.81873075307798182354f;

    const int tid = threadIdx.x;
    const int gid = blockIdx.x * 64 + tid;
    const size_t base = ((size_t)(gid >> 9)) * (size_t)Tsz * Hsz + (gid & 511);

    float v = 0.f, isyn = 0.f, acc = 0.f;
    constexpr int P = 8;
    float ring[P];
#pragma unroll
    for (int p = 0; p < P; ++p) ring[p] = cur[base + (size_t)p * Hsz];

    for (int t = 0; t < Tsz; t += P) {
#pragma unroll
        for (int p = 0; p < P; ++p) {
            const float c = ring[p];
            int tn = t + P + p;
            tn = tn < (Tsz - 1) ? tn : (Tsz - 1);
            ring[p] = cur[base + (size_t)tn * Hsz];

            isyn = fmaf(A_S, isyn, c);
            v    = fmaf(A_M, v, OM_M * isyn);
            const float sp = (v >= 1.0f) ? 1.0f : 0.0f;
            const float x  = 4.0f * (v - 1.0f);
            const float surr = 4.0f / (2.0f + __expf(x) + __expf(-x));
            const float so   = fmaf(2.0f, sp, -surr);
            v = (sp > 0.f) ? 0.0f : v;

            const size_t idx = base + (size_t)(t + p) * Hsz;
            spikes[idx] = so;
            vmem[idx]   = v;
            acc += so;
        }
    }
    vfinal[gid] = v;
#pragma unroll
    for (int off = 32; off; off >>= 1) acc += __shfl_down(acc, off);
    if (tid == 0) partials[blockIdx.x] = acc;
}

__global__ __launch_bounds__(256) void rate_finalize(
    const float* __restrict__ partials, float* __restrict__ rate)
{
    const int tid = threadIdx.x;
    float s = partials[tid];
#pragma unroll
    for (int off = 32; off; off >>= 1) s += __shfl_down(s, off);
    __shared__ float wsum[4];
    if ((tid & 63) == 0) wsum[tid >> 6] = s;
    __syncthreads();
    if (tid == 0)
        rate[0] = ((wsum[0] + wsum[1]) + (wsum[2] + wsum[3])) * (1.0f / 16777216.0f);
}

// ===========================================================================
extern "C" void kernel_launch(void* const* d_in, const int* in_sizes, int n_in,
                              void* d_out, int out_size, void* d_ws, size_t ws_size,
                              hipStream_t stream)
{
    const float* inputs = (const float*)d_in[0];
    const float* weight = (const float*)d_in[1];
    const float* bias   = (const float*)d_in[2];

    float* out    = (float*)d_out;
    float* spikes = out;
    float* vmem   = out + ELEMS;
    float* vfinal = out + 2 * ELEMS;
    float* rate   = vfinal + (size_t)Bsz * Hsz;

    float* partials = (float*)d_ws;
    char*  ws       = (char*)d_ws;

    const size_t CUR_B = ELEMS * 4;          // 64 MiB
    const size_t ALV_B = 3 * ELEMS * 2;      // 96 MiB
    const size_t BLV_B = 3 * BELEM * 2;      // 1.5 MiB

    ushort_t *A0, *A1, *A2, *B0, *B1, *B2;
    float* cur;
    int path;
    if (ws_size >= 4096 + CUR_B + ALV_B + BLV_B) {
        cur = (float*)(ws + 4096);
        A0 = (ushort_t*)(ws + 4096 + CUR_B); A1 = A0 + ELEMS; A2 = A1 + ELEMS;
        B0 = A2 + ELEMS; B1 = B0 + BELEM; B2 = B1 + BELEM;
        path = 0;
    } else if (ws_size >= 4096 + CUR_B) {
        cur = (float*)(ws + 4096);
        A0 = (ushort_t*)d_out; A1 = A0 + ELEMS; A2 = A1 + ELEMS;
        B0 = A2 + ELEMS; B1 = B0 + BELEM; B2 = B1 + BELEM;
        path = 1;
    } else {
        cur = vmem;
        A0 = A1 = A2 = B0 = B1 = B2 = nullptr;
        path = 2;
    }

    if (path != 2) {
        split_bf16x3<<<dim3(4096 + 256), 256, 0, stream>>>(inputs, weight,
                                                           A0, A1, A2, B0, B1, B2);
        gemm_limb<<<dim3(1024), 256, 0, stream>>>(A0, A1, A2, B0, B1, B2, bias, cur);
        lif_scan_r<<<dim3(256), 64, 0, stream>>>(cur, spikes, vmem, vfinal, partials);
    } else {
        sgemm_currents<<<dim3(4, 256), 256, 0, stream>>>(inputs, weight, bias, cur);
        lif_scan<<<dim3(256), 64, 0, stream>>>(cur, spikes, vmem, vfinal, partials);
    }
    rate_finalize<<<dim3(1), 256, 0, stream>>>(partials, rate);
}

// Round 5
// 210.301 us; speedup vs baseline: 2.2600x; 1.1183x over previous
//
#include <hip/hip_runtime.h>

typedef unsigned short ushort_t;
typedef unsigned int   uint_t;
typedef float  float4v __attribute__((ext_vector_type(4)));
typedef __bf16 bf16x8  __attribute__((ext_vector_type(8)));

#define Bsz 32
#define Tsz 1024
#define Din 512
#define Hsz 512
#define Mtot (Bsz * Tsz)                 // 32768
#define ELEMS ((size_t)Mtot * Hsz)       // 16777216
#define BELEM ((size_t)Din * Hsz)        // 262144 per B limb

#define GLL16(gp, lp) __builtin_amdgcn_global_load_lds(                        \
    (const __attribute__((address_space(1))) unsigned int*)(gp),               \
    (__attribute__((address_space(3))) unsigned int*)(lp), 16, 0, 0)

// ===========================================================================
// Pass 1: exact 3-way bf16 truncation split (x == h0+h1+h2 bitwise).
// ===========================================================================
__device__ __forceinline__ void split3(float c, uint_t& h0, uint_t& h1, uint_t& h2)
{
    uint_t t0 = __float_as_uint(c) & 0xFFFF0000u;
    float  r1 = c - __uint_as_float(t0);
    uint_t t1 = __float_as_uint(r1) & 0xFFFF0000u;
    float  r2 = r1 - __uint_as_float(t1);
    uint_t t2 = __float_as_uint(r2) & 0xFFFF0000u;
    h0 = t0 >> 16; h1 = t1 >> 16; h2 = t2 >> 16;
}

__global__ __launch_bounds__(256) void split_bf16x3(
    const float* __restrict__ A, const float* __restrict__ W,
    ushort_t* __restrict__ A0, ushort_t* __restrict__ A1, ushort_t* __restrict__ A2,
    ushort_t* __restrict__ B0, ushort_t* __restrict__ B1, ushort_t* __restrict__ B2)
{
    const int bid = blockIdx.x, tid = threadIdx.x;
    if (bid < 4096) {                       // A split
        const float4* Af = (const float4*)A;
#pragma unroll
        for (int q = 0; q < 4; ++q) {
            const size_t i = (size_t)bid * 1024 + q * 256 + tid;
            float4 x = Af[i];
            const float c[4] = {x.x, x.y, x.z, x.w};
            uint_t h0[4], h1[4], h2[4];
#pragma unroll
            for (int j = 0; j < 4; ++j) split3(c[j], h0[j], h1[j], h2[j]);
            *(uint2*)(A0 + 4 * i) = make_uint2(h0[0] | (h0[1] << 16), h0[2] | (h0[3] << 16));
            *(uint2*)(A1 + 4 * i) = make_uint2(h1[0] | (h1[1] << 16), h1[2] | (h1[3] << 16));
            *(uint2*)(A2 + 4 * i) = make_uint2(h2[0] | (h2[1] << 16), h2[2] | (h2[3] << 16));
        }
    } else {                                // W split + transpose (1.5 MiB, cheap)
        const int f4 = (bid - 4096) * 256 + tid;
        const int k  = f4 >> 7;
        const int n4 = (f4 & 127) << 2;
        float4 x = *(const float4*)(W + (size_t)k * Hsz + n4);
        const float c[4] = {x.x, x.y, x.z, x.w};
#pragma unroll
        for (int j = 0; j < 4; ++j) {
            uint_t h0, h1, h2;
            split3(c[j], h0, h1, h2);
            const size_t o = (size_t)(n4 + j) * Din + k;
            B0[o] = (ushort_t)h0; B1[o] = (ushort_t)h1; B2[o] = (ushort_t)h2;
        }
    }
}

// ===========================================================================
// Pass 2: bf16x3 MFMA GEMM, virtual K = 6 pairs x 512 = 96 K-tiles of 32.
// Counted-vmcnt tri-buffer pipeline:
//   256x256 tile, 512 thr (8 waves 2Mx4N, per-wave 128x64), BK=32.
//   3 LDS buffers (96 KiB): staging for K-tile T+2 issued during T's two
//   phases; boundary gate = vmcnt(4) (this K-tile's 4 stage-loads stay in
//   flight) + raw s_barrier. Loads NEVER drain to 0 in the main loop.
//   Phase = {ds_read frags | issue 2 global_load_lds | setprio(1) 16 MFMA}.
// Swizzle: 4 chunks/64B-row, phys = logical ^ (row&3) ^ ((row>>2)&3);
// linear LDS dest + inverse-swizzled global source + swizzled ds_read.
// Pair order: (A0,B0)(A0,B1)(A0,B2)(A1,B0)(A1,B1)(A2,B0).
// ===========================================================================
#define ASTRIDE 16384   // bytes per LDS buffer (256 rows x 64 B)

#define STAGE_A(S, bb) {                                                       \
    const int p_ = (S) >> 4;                                                   \
    const ushort_t* Al_ = (p_ < 3) ? A0 : ((p_ < 5) ? A1 : A2);                \
    const char* g_ = (const char*)Al_ + sgA + (((S) & 15) << 6);               \
    char* l_ = (char*)As + (bb) * ASTRIDE + sl;                                \
    GLL16(g_, l_); GLL16(g_ + 131072, l_ + 8192); }

#define STAGE_B(S, bb) {                                                       \
    const int p_ = (S) >> 4;                                                   \
    const ushort_t* Bl_ = (p_ == 2) ? B2 : ((p_ == 1 || p_ == 4) ? B1 : B0);   \
    const char* g_ = (const char*)Bl_ + sgB + (((S) & 15) << 6);               \
    char* l_ = (char*)Bs + (bb) * ASTRIDE + sl;                                \
    GLL16(g_, l_); GLL16(g_ + 131072, l_ + 8192); }

__global__ __launch_bounds__(512, 2) void gemm_limb8(
    const ushort_t* __restrict__ A0, const ushort_t* __restrict__ A1,
    const ushort_t* __restrict__ A2,
    const ushort_t* __restrict__ B0, const ushort_t* __restrict__ B1,
    const ushort_t* __restrict__ B2,
    const float* __restrict__ bias, float* __restrict__ C)
{
    __shared__ __align__(16) ushort_t As[3 * 8192];   // 48 KiB
    __shared__ __align__(16) ushort_t Bs[3 * 8192];   // 48 KiB

    const int tid = threadIdx.x;
    const int bid = blockIdx.x;
    // XCD-bijective swizzle (nwg=256, %8==0)
    const int lin = ((bid & 7) << 5) | (bid >> 3);
    const int m0  = (lin >> 1) << 8;                  // 128 m-panels x 256
    const int n0  = (lin & 1) << 8;                   // 2 n-panels x 256
    const int w = tid >> 6, lane = tid & 63;
    const int wm = (w & 1) << 7;                      // 2 M-warps x 128
    const int wn = (w >> 1) << 6;                     // 4 N-warps x 64
    const int lr = lane & 15, lg = lane >> 4;

    // frag-read lane constants (swizzled chunk)
    const int physf = lg ^ (lr & 3) ^ ((lr >> 2) & 3);
    const int aro = (wm + lr) * 64 + physf * 16;      // + mf*1024
    const int bro = (wn + lr) * 64 + physf * 16;      // + nf*1024

    // staging lane constants: row = tid>>2 (+128 per round), phys chunk = tid&3
    const int srow = tid >> 2;
    const int schk = tid & 3;
    const int logchk = schk ^ ((tid >> 2) & 3) ^ ((tid >> 4) & 3);
    const size_t sgA = (size_t)(m0 + srow) * 1024 + (size_t)(logchk * 16);
    const size_t sgB = (size_t)(n0 + srow) * 1024 + (size_t)(logchk * 16);
    const int    sl  = srow * 64 + schk * 16;

    float4v acc[8][4];
#pragma unroll
    for (int i = 0; i < 8; ++i)
#pragma unroll
        for (int j = 0; j < 4; ++j) acc[i][j] = (float4v)0.f;

    // prologue: K-tiles 0 and 1 into buffers 0,1
    STAGE_A(0, 0); STAGE_B(0, 0);
    STAGE_A(1, 1); STAGE_B(1, 1);
    asm volatile("s_waitcnt vmcnt(4)" ::: "memory");
    __builtin_amdgcn_sched_barrier(0);
    __builtin_amdgcn_s_barrier();
    asm volatile("" ::: "memory");

    int cb = 0;
#pragma unroll 1
    for (int T = 0; T < 96; ++T) {
        const int nx = (cb == 0) ? 2 : (cb - 1);      // (cb+2)%3
        const char* ab = (const char*)As + cb * ASTRIDE;
        const char* bb = (const char*)Bs + cb * ASTRIDE;

        bf16x8 af[4], bf[4];
        // -------- phase 0: frags + A-stage + MFMA (mf 0..3)
#pragma unroll
        for (int nf = 0; nf < 4; ++nf) bf[nf] = *(const bf16x8*)(bb + bro + nf * 1024);
#pragma unroll
        for (int mf = 0; mf < 4; ++mf) af[mf] = *(const bf16x8*)(ab + aro + mf * 1024);
        if (T < 94) STAGE_A(T + 2, nx);
        __builtin_amdgcn_s_setprio(1);
#pragma unroll
        for (int mf = 0; mf < 4; ++mf)
#pragma unroll
            for (int nf = 0; nf < 4; ++nf)
                acc[mf][nf] = __builtin_amdgcn_mfma_f32_16x16x32_bf16(
                    af[mf], bf[nf], acc[mf][nf], 0, 0, 0);
        __builtin_amdgcn_s_setprio(0);
        // -------- phase 1: frags + B-stage + MFMA (mf 4..7)
#pragma unroll
        for (int mf = 0; mf < 4; ++mf) af[mf] = *(const bf16x8*)(ab + aro + (mf + 4) * 1024);
        if (T < 94) STAGE_B(T + 2, nx);
        __builtin_amdgcn_s_setprio(1);
#pragma unroll
        for (int mf = 0; mf < 4; ++mf)
#pragma unroll
            for (int nf = 0; nf < 4; ++nf)
                acc[mf + 4][nf] = __builtin_amdgcn_mfma_f32_16x16x32_bf16(
                    af[mf], bf[nf], acc[mf + 4][nf], 0, 0, 0);
        __builtin_amdgcn_s_setprio(0);
        // -------- boundary gate (counted; never drains in steady state)
        if (T < 95) {
            if (T <= 93) asm volatile("s_waitcnt vmcnt(4)" ::: "memory");
            else         asm volatile("s_waitcnt vmcnt(0)" ::: "memory");
            __builtin_amdgcn_sched_barrier(0);
            __builtin_amdgcn_s_barrier();
            asm volatile("" ::: "memory");
        }
        cb = (cb == 2) ? 0 : cb + 1;
    }

    // epilogue: C/D map (verified R2-R4): col side = lr, row side = lg*4+j
#pragma unroll
    for (int nf = 0; nf < 4; ++nf) {
        const int col = n0 + wn + nf * 16 + lr;
        const float bv = bias[col];
#pragma unroll
        for (int mf = 0; mf < 8; ++mf)
#pragma unroll
            for (int j = 0; j < 4; ++j) {
                const int row = m0 + wm + mf * 16 + lg * 4 + j;
                C[(size_t)row * Hsz + col] = acc[mf][nf][j] + bv;
            }
    }
}

// ===========================================================================
// Fallback fp32 GEMM (only if d_ws too small for bf16x3 path)
// ===========================================================================
#define BM 128
#define BN 128
#define BK 16
#define LDSA (BM + 4)
#define LDSB (BN + 4)
__global__ __launch_bounds__(256) void sgemm_currents(
    const float* __restrict__ A, const float* __restrict__ B,
    const float* __restrict__ bias, float* __restrict__ C)
{
    __shared__ float As[BK][LDSA];
    __shared__ float Bs[BK][LDSB];
    const int tid = threadIdx.x;
    const int tx = tid & 15, ty = tid >> 4;
    const int m0 = blockIdx.y * BM, n0 = blockIdx.x * BN;
    const int arow = tid >> 2, ac4 = (tid & 3) * 4;
    const int brow = tid >> 5, bc4 = (tid & 31) * 4;
    float acc[8][8];
#pragma unroll
    for (int i = 0; i < 8; ++i)
#pragma unroll
        for (int j = 0; j < 8; ++j) acc[i][j] = 0.f;
    const float* Abase = A + (size_t)(m0 + arow) * Din + ac4;
    const float* Bbase = B + (size_t)brow * Hsz + n0 + bc4;
    float4 a0 = *(const float4*)Abase;
    float4 a1 = *(const float4*)(Abase + (size_t)64 * Din);
    float4 b0 = *(const float4*)Bbase;
    float4 b1 = *(const float4*)(Bbase + (size_t)8 * Hsz);
    const int NKT = Din / BK;
    for (int kt = 0; kt < NKT; ++kt) {
        const float* apf = (const float*)&a0;
        const float* aqf = (const float*)&a1;
#pragma unroll
        for (int j = 0; j < 4; ++j) As[ac4 + j][arow] = apf[j];
#pragma unroll
        for (int j = 0; j < 4; ++j) As[ac4 + j][arow + 64] = aqf[j];
        *(float4*)&Bs[brow][bc4] = b0;
        *(float4*)&Bs[brow + 8][bc4] = b1;
        __syncthreads();
        if (kt + 1 < NKT) {
            const float* An = Abase + (kt + 1) * BK;
            const float* Bn = Bbase + (size_t)(kt + 1) * BK * Hsz;
            a0 = *(const float4*)An;
            a1 = *(const float4*)(An + (size_t)64 * Din);
            b0 = *(const float4*)Bn;
            b1 = *(const float4*)(Bn + (size_t)8 * Hsz);
        }
#pragma unroll
        for (int k = 0; k < BK; ++k) {
            float4 af0 = *(const float4*)&As[k][ty * 8];
            float4 af1 = *(const float4*)&As[k][ty * 8 + 4];
            float4 bf0 = *(const float4*)&Bs[k][tx * 8];
            float4 bf1 = *(const float4*)&Bs[k][tx * 8 + 4];
            const float av[8] = {af0.x, af0.y, af0.z, af0.w, af1.x, af1.y, af1.z, af1.w};
            const float bv[8] = {bf0.x, bf0.y, bf0.z, bf0.w, bf1.x, bf1.y, bf1.z, bf1.w};
#pragma unroll
            for (int i = 0; i < 8; ++i)
#pragma unroll
                for (int j = 0; j < 8; ++j) acc[i][j] = fmaf(av[i], bv[j], acc[i][j]);
        }
        __syncthreads();
    }
    const float4 bi0 = *(const float4*)&bias[n0 + tx * 8];
    const float4 bi1 = *(const float4*)&bias[n0 + tx * 8 + 4];
#pragma unroll
    for (int i = 0; i < 8; ++i) {
        const size_t row = (size_t)(m0 + ty * 8 + i);
        float4 o0 = make_float4(acc[i][0] + bi0.x, acc[i][1] + bi0.y,
                                acc[i][2] + bi0.z, acc[i][3] + bi0.w);
        float4 o1 = make_float4(acc[i][4] + bi1.x, acc[i][5] + bi1.y,
                                acc[i][6] + bi1.z, acc[i][7] + bi1.w);
        float* cp = C + row * Hsz + n0 + tx * 8;
        *(float4*)cp = o0;
        *(float4*)(cp + 4) = o1;
    }
}

// ===========================================================================
// LIF step math: surr = 4/(2+e^x+e^-x) = 4*e^x/(1+e^x)^2  -> 1 exp + 1 rcp.
// surr feeds only the output (not the recursion), so v_rcp_f32 precision
// (~1e-7) is harmless. Clamp x<=30 to avoid inf*0 -> NaN.
// ===========================================================================
__device__ __forceinline__ void lif_step(float c, float& v, float& isyn,
                                         float& so_out)
{
    constexpr float A_M  = 0.95122942450071400910f;
    constexpr float OM_M = 1.0f - A_M;
    constexpr float A_S  = 0.81873075307798182354f;
    isyn = fmaf(A_S, isyn, c);
    v    = fmaf(A_M, v, OM_M * isyn);
    const float sp = (v >= 1.0f) ? 1.0f : 0.0f;
    float x = fmaf(4.0f, v, -4.0f);
    x = fminf(x, 30.0f);
    const float ep = __expf(x);
    const float tt = 1.0f + ep;
    const float surr = 4.0f * ep * __builtin_amdgcn_rcpf(tt * tt);
    so_out = fmaf(2.0f, sp, -surr);
    v = (sp > 0.f) ? 0.0f : v;
}

// ===========================================================================
// Pass 3a: LIF scan, NON-ALIASED path. 256 blocks x 64 thr = 1 wave/CU;
// P=32 register ring keeps 32 loads in flight; nontemporal output stores.
// ===========================================================================
__global__ __launch_bounds__(64) void lif_scan_r(
    const float* __restrict__ cur, float* __restrict__ spikes,
    float* __restrict__ vmem, float* __restrict__ vfinal,
    float* __restrict__ partials)
{
    const int tid = threadIdx.x;
    const int gid = blockIdx.x * 64 + tid;
    const size_t base = ((size_t)(gid >> 9)) * (size_t)Tsz * Hsz + (gid & 511);

    float v = 0.f, isyn = 0.f, acc = 0.f;
    constexpr int P = 32;
    float ring[P];
#pragma unroll
    for (int p = 0; p < P; ++p) ring[p] = cur[base + (size_t)p * Hsz];

    for (int t = 0; t < Tsz; t += P) {
#pragma unroll
        for (int p = 0; p < P; ++p) {
            const float c = ring[p];
            int tn = t + P + p;
            tn = tn < (Tsz - 1) ? tn : (Tsz - 1);
            ring[p] = cur[base + (size_t)tn * Hsz];

            float so;
            lif_step(c, v, isyn, so);
            const size_t idx = base + (size_t)(t + p) * Hsz;
            __builtin_nontemporal_store(so, &spikes[idx]);
            __builtin_nontemporal_store(v,  &vmem[idx]);
            acc += so;
        }
    }
    vfinal[gid] = v;
#pragma unroll
    for (int off = 32; off; off >>= 1) acc += __shfl_down(acc, off);
    if (tid == 0) partials[blockIdx.x] = acc;
}

// ===========================================================================
// Pass 3b: LIF scan, ALIAS-SAFE fallback (cur may be the vmem region).
// ===========================================================================
__global__ __launch_bounds__(64) void lif_scan(
    const float* cur, float* spikes, float* vmem, float* vfinal, float* partials)
{
    const int tid = threadIdx.x;
    const int gid = blockIdx.x * 64 + tid;
    const size_t base = ((size_t)(gid >> 9)) * (size_t)Tsz * Hsz + (gid & 511);

    float v = 0.f, isyn = 0.f, acc = 0.f;
    constexpr int P = 8;
    float ring[P];
#pragma unroll
    for (int p = 0; p < P; ++p) ring[p] = cur[base + (size_t)p * Hsz];

    for (int t = 0; t < Tsz; t += P) {
#pragma unroll
        for (int p = 0; p < P; ++p) {
            const float c = ring[p];
            int tn = t + P + p;
            tn = tn < (Tsz - 1) ? tn : (Tsz - 1);
            ring[p] = cur[base + (size_t)tn * Hsz];

            float so;
            lif_step(c, v, isyn, so);
            const size_t idx = base + (size_t)(t + p) * Hsz;
            spikes[idx] = so;
            vmem[idx]   = v;
            acc += so;
        }
    }
    vfinal[gid] = v;
#pragma unroll
    for (int off = 32; off; off >>= 1) acc += __shfl_down(acc, off);
    if (tid == 0) partials[blockIdx.x] = acc;
}

__global__ __launch_bounds__(256) void rate_finalize(
    const float* __restrict__ partials, float* __restrict__ rate)
{
    const int tid = threadIdx.x;
    float s = partials[tid];
#pragma unroll
    for (int off = 32; off; off >>= 1) s += __shfl_down(s, off);
    __shared__ float wsum[4];
    if ((tid & 63) == 0) wsum[tid >> 6] = s;
    __syncthreads();
    if (tid == 0)
        rate[0] = ((wsum[0] + wsum[1]) + (wsum[2] + wsum[3])) * (1.0f / 16777216.0f);
}

// ===========================================================================
extern "C" void kernel_launch(void* const* d_in, const int* in_sizes, int n_in,
                              void* d_out, int out_size, void* d_ws, size_t ws_size,
                              hipStream_t stream)
{
    const float* inputs = (const float*)d_in[0];
    const float* weight = (const float*)d_in[1];
    const float* bias   = (const float*)d_in[2];

    float* out    = (float*)d_out;
    float* spikes = out;
    float* vmem   = out + ELEMS;
    float* vfinal = out + 2 * ELEMS;
    float* rate   = vfinal + (size_t)Bsz * Hsz;

    float* partials = (float*)d_ws;
    char*  ws       = (char*)d_ws;

    const size_t CUR_B = ELEMS * 4;          // 64 MiB
    const size_t ALV_B = 3 * ELEMS * 2;      // 96 MiB
    const size_t BLV_B = 3 * BELEM * 2;      // 1.5 MiB

    ushort_t *A0, *A1, *A2, *B0, *B1, *B2;
    float* cur;
    int path;
    if (ws_size >= 4096 + CUR_B + ALV_B + BLV_B) {
        cur = (float*)(ws + 4096);
        A0 = (ushort_t*)(ws + 4096 + CUR_B); A1 = A0 + ELEMS; A2 = A1 + ELEMS;
        B0 = A2 + ELEMS; B1 = B0 + BELEM; B2 = B1 + BELEM;
        path = 0;
    } else if (ws_size >= 4096 + CUR_B) {
        cur = (float*)(ws + 4096);
        A0 = (ushort_t*)d_out; A1 = A0 + ELEMS; A2 = A1 + ELEMS;
        B0 = A2 + ELEMS; B1 = B0 + BELEM; B2 = B1 + BELEM;
        path = 1;
    } else {
        cur = vmem;
        A0 = A1 = A2 = B0 = B1 = B2 = nullptr;
        path = 2;
    }

    if (path != 2) {
        split_bf16x3<<<dim3(4096 + 256), 256, 0, stream>>>(inputs, weight,
                                                           A0, A1, A2, B0, B1, B2);
        gemm_limb8<<<dim3(256), 512, 0, stream>>>(A0, A1, A2, B0, B1, B2, bias, cur);
        lif_scan_r<<<dim3(256), 64, 0, stream>>>(cur, spikes, vmem, vfinal, partials);
    } else {
        sgemm_currents<<<dim3(4, 256), 256, 0, stream>>>(inputs, weight, bias, cur);
        lif_scan<<<dim3(256), 64, 0, stream>>>(cur, spikes, vmem, vfinal, partials);
    }
    rate_finalize<<<dim3(1), 256, 0, stream>>>(partials, rate);
}

// Round 6
// 193.992 us; speedup vs baseline: 2.4500x; 1.0841x over previous
//
#include <hip/hip_runtime.h>

typedef unsigned short ushort_t;
typedef unsigned int   uint_t;
typedef float  float4v __attribute__((ext_vector_type(4)));
typedef __bf16 bf16x8  __attribute__((ext_vector_type(8)));

#define Bsz 32
#define Tsz 1024
#define Din 512
#define Hsz 512
#define Mtot (Bsz * Tsz)                 // 32768
#define ELEMS ((size_t)Mtot * Hsz)       // 16777216
#define BELEM ((size_t)Din * Hsz)        // 262144 per B limb

#define GLL16(gp, lp) __builtin_amdgcn_global_load_lds(                        \
    (const __attribute__((address_space(1))) unsigned int*)(gp),               \
    (__attribute__((address_space(3))) unsigned int*)(lp), 16, 0, 0)

// ===========================================================================
// Pass 1: exact 3-way bf16 truncation split (x == h0+h1+h2 bitwise).
// ===========================================================================
__device__ __forceinline__ void split3(float c, uint_t& h0, uint_t& h1, uint_t& h2)
{
    uint_t t0 = __float_as_uint(c) & 0xFFFF0000u;
    float  r1 = c - __uint_as_float(t0);
    uint_t t1 = __float_as_uint(r1) & 0xFFFF0000u;
    float  r2 = r1 - __uint_as_float(t1);
    uint_t t2 = __float_as_uint(r2) & 0xFFFF0000u;
    h0 = t0 >> 16; h1 = t1 >> 16; h2 = t2 >> 16;
}

__global__ __launch_bounds__(256) void split_bf16x3(
    const float* __restrict__ A, const float* __restrict__ W,
    ushort_t* __restrict__ A0, ushort_t* __restrict__ A1, ushort_t* __restrict__ A2,
    ushort_t* __restrict__ B0, ushort_t* __restrict__ B1, ushort_t* __restrict__ B2)
{
    const int bid = blockIdx.x, tid = threadIdx.x;
    if (bid < 4096) {                       // A split
        const float4* Af = (const float4*)A;
#pragma unroll
        for (int q = 0; q < 4; ++q) {
            const size_t i = (size_t)bid * 1024 + q * 256 + tid;
            float4 x = Af[i];
            const float c[4] = {x.x, x.y, x.z, x.w};
            uint_t h0[4], h1[4], h2[4];
#pragma unroll
            for (int j = 0; j < 4; ++j) split3(c[j], h0[j], h1[j], h2[j]);
            *(uint2*)(A0 + 4 * i) = make_uint2(h0[0] | (h0[1] << 16), h0[2] | (h0[3] << 16));
            *(uint2*)(A1 + 4 * i) = make_uint2(h1[0] | (h1[1] << 16), h1[2] | (h1[3] << 16));
            *(uint2*)(A2 + 4 * i) = make_uint2(h2[0] | (h2[1] << 16), h2[2] | (h2[3] << 16));
        }
    } else {                                // W split + transpose (1.5 MiB, cheap)
        const int f4 = (bid - 4096) * 256 + tid;
        const int k  = f4 >> 7;
        const int n4 = (f4 & 127) << 2;
        float4 x = *(const float4*)(W + (size_t)k * Hsz + n4);
        const float c[4] = {x.x, x.y, x.z, x.w};
#pragma unroll
        for (int j = 0; j < 4; ++j) {
            uint_t h0, h1, h2;
            split3(c[j], h0, h1, h2);
            const size_t o = (size_t)(n4 + j) * Din + k;
            B0[o] = (ushort_t)h0; B1[o] = (ushort_t)h1; B2[o] = (ushort_t)h2;
        }
    }
}

// ===========================================================================
// Pass 2: bf16x3 MFMA GEMM with register-level operand reuse.
// Tile 256x128, 256 thr (4 waves 2Mx2N, per-wave 128x64), phase = (k, limb
// pair); group of 6 phases per k: (A0B0)(A0B1)(A0B2)(A1B0)(A1B1)(A2B0).
//  - af[8] reloaded at j=0/3/5 (A-limb change), bf0/1/2[4] loaded at j=0/1/2
//    and register-reused at j=3/4/5  -> LDS reads 36 KB/group (was 72).
//  - A staged once per 3 uses, B once per use -> DMA 72 KB/group (was 192).
//  - LDS: A-ring 3x16K + B-ring 4x8K = 80 KB -> 2 blocks/CU.
//  - Uniform 3 global_load_lds issues/phase -> uniform vmcnt(6) gates
//    (guarantee: issues <= p-2 complete; all deadlines are >= issue+2).
//  - chunk-XOR swizzle as R5 (linear LDS dest, pre-swizzled global source).
// ===========================================================================
#define STG_A(PTR, KK, H, SLOT) do {                                           \
    const char* g_ = (const char*)(PTR) + gA + (size_t)((KK) * 64)             \
                     + (size_t)((H) * 131072);                                 \
    char* l_ = ldsb + (SLOT) * 16384 + (H) * 8192 + lsd;                       \
    GLL16(g_, l_); GLL16(g_ + 65536, l_ + 4096); } while (0)

#define STG_B(PTR, KK, H, SLOT) do {                                           \
    const char* g_ = (const char*)(PTR) + gB + (size_t)((KK) * 64)             \
                     + (size_t)((H) * 65536);                                  \
    char* l_ = ldsb + 49152 + (SLOT) * 8192 + (H) * 4096 + lsd;                \
    GLL16(g_, l_); } while (0)

#define LD_AF(SLOT) do { const char* b_ = ldsb + (SLOT) * 16384;               \
    _Pragma("unroll") for (int mf = 0; mf < 8; ++mf)                           \
        af[mf] = *(const bf16x8*)(b_ + (wm + mf * 16) * 64 + aro); } while (0)

#define LD_BF(DST, SLOT) do { const char* b_ = ldsb + 49152 + (SLOT) * 8192;   \
    _Pragma("unroll") for (int nf = 0; nf < 4; ++nf)                           \
        DST[nf] = *(const bf16x8*)(b_ + (wn + nf * 16) * 64 + bro); } while (0)

#define MFMA32(BF) do { __builtin_amdgcn_s_setprio(1);                         \
    _Pragma("unroll") for (int mf = 0; mf < 8; ++mf)                           \
    _Pragma("unroll") for (int nf = 0; nf < 4; ++nf)                           \
        acc[mf][nf] = __builtin_amdgcn_mfma_f32_16x16x32_bf16(                 \
            af[mf], BF[nf], acc[mf][nf], 0, 0, 0);                             \
    __builtin_amdgcn_s_setprio(0); } while (0)

#define GATE(N) do { asm volatile("s_waitcnt vmcnt(" #N ")" ::: "memory");     \
    __builtin_amdgcn_sched_barrier(0); __builtin_amdgcn_s_barrier();           \
    asm volatile("" ::: "memory"); } while (0)

__global__ __launch_bounds__(256, 2) void gemm_limb6(
    const ushort_t* __restrict__ A0, const ushort_t* __restrict__ A1,
    const ushort_t* __restrict__ A2,
    const ushort_t* __restrict__ B0, const ushort_t* __restrict__ B1,
    const ushort_t* __restrict__ B2,
    const float* __restrict__ bias, float* __restrict__ C)
{
    __shared__ __align__(16) char lds[81920];   // A: 3*16K @0, B: 4*8K @49152
    char* ldsb = lds;

    const int tid = threadIdx.x;
    const int bid = blockIdx.x;
    // XCD-bijective swizzle (nwg=512, %8==0)
    const int lin = ((bid & 7) << 6) | (bid >> 3);
    const int m0  = (lin >> 2) << 8;          // 128 m-panels x 256
    const int n0  = (lin & 3) << 7;           // 4 n-panels x 128
    const int w = tid >> 6, lane = tid & 63;
    const int wm = (w & 1) << 7;              // 0 / 128
    const int wn = (w >> 1) << 6;             // 0 / 64
    const int lr = lane & 15, lg = lane >> 4;

    // frag-read constants (swizzled chunk); physf invariant under wm/wn/mf/nf
    const int physf = lg ^ (lr & 3) ^ ((lr >> 2) & 3);
    const int aro = lr * 64 + physf * 16;
    const int bro = lr * 64 + physf * 16;

    // staging constants: linear LDS dest tid*16; inverse-swizzled global src
    const int srow = tid >> 2;
    const int schk = tid & 3;
    const int logchk = schk ^ (srow & 3) ^ ((srow >> 2) & 3);
    const int lsd = tid * 16;
    const size_t gA = (size_t)(m0 + srow) * 1024 + (size_t)(logchk * 16);
    const size_t gB = (size_t)(n0 + srow) * 1024 + (size_t)(logchk * 16);

    float4v acc[8][4];
#pragma unroll
    for (int i = 0; i < 8; ++i)
#pragma unroll
        for (int j = 0; j < 4; ++j) acc[i][j] = (float4v)0.f;

    bf16x8 af[8], bf0[4], bf1[4], bf2[4];

    // prologue: A0[0]->slot0, A1[0]->slot1, B chunks 0,1,2 -> slots 0,1,2
    STG_A(A0, 0, 0, 0); STG_A(A0, 0, 1, 0);
    STG_A(A1, 0, 0, 1); STG_A(A1, 0, 1, 1);
    STG_B(B0, 0, 0, 0); STG_B(B0, 0, 1, 0);
    STG_B(B1, 0, 0, 1); STG_B(B1, 0, 1, 1);
    STG_B(B2, 0, 0, 2); STG_B(B2, 0, 1, 2);
    GATE(0);

#pragma unroll 1
    for (int k = 0; k < 15; ++k) {
        const int br = (3 * k) & 3;           // B-read slot base (chunk 3k)
        const int bw = (br + 3) & 3;          // B-write slot base (chunk 3k+3)
        // ---- j=0: pair (A0,B0)
        LD_AF(0); LD_BF(bf0, br);
        STG_A(A2, k, 0, 2);  STG_B(B0, k + 1, 0, bw);
        MFMA32(bf0); GATE(6);
        // ---- j=1: (A0,B1)
        LD_BF(bf1, (br + 1) & 3);
        STG_A(A2, k, 1, 2);  STG_B(B0, k + 1, 1, bw);
        MFMA32(bf1); GATE(6);
        // ---- j=2: (A0,B2)
        LD_BF(bf2, (br + 2) & 3);
        STG_A(A0, k + 1, 0, 0);  STG_B(B1, k + 1, 0, (bw + 1) & 3);
        MFMA32(bf2); GATE(6);
        // ---- j=3: (A1,B0)
        LD_AF(1);
        STG_A(A0, k + 1, 1, 0);  STG_B(B1, k + 1, 1, (bw + 1) & 3);
        MFMA32(bf0); GATE(6);
        // ---- j=4: (A1,B1)
        STG_A(A1, k + 1, 0, 1);  STG_B(B2, k + 1, 0, (bw + 2) & 3);
        MFMA32(bf1); GATE(6);
        // ---- j=5: (A2,B0)
        LD_AF(2);
        STG_A(A1, k + 1, 1, 1);  STG_B(B2, k + 1, 1, (bw + 2) & 3);
        MFMA32(bf0); GATE(6);
    }

    {   // peeled group k=15 (phases 90..95), tapered gates
        LD_AF(0); LD_BF(bf0, 1);              // chunk 45 -> slot 45&3 = 1
        STG_A(A2, 15, 0, 2);
        MFMA32(bf0); GATE(5);
        LD_BF(bf1, 2);                        // chunk 46
        STG_A(A2, 15, 1, 2);
        MFMA32(bf1); GATE(4);
        LD_BF(bf2, 3);                        // chunk 47
        MFMA32(bf2); GATE(2);
        LD_AF(1);
        MFMA32(bf0); GATE(0);
        MFMA32(bf1); GATE(0);
        LD_AF(2);
        MFMA32(bf0);
    }

    // epilogue: C/D map (verified R2-R5): col side = lr, row side = lg*4+j
#pragma unroll
    for (int nf = 0; nf < 4; ++nf) {
        const int col = n0 + wn + nf * 16 + lr;
        const float bv = bias[col];
#pragma unroll
        for (int mf = 0; mf < 8; ++mf)
#pragma unroll
            for (int j = 0; j < 4; ++j) {
                const int row = m0 + wm + mf * 16 + lg * 4 + j;
                C[(size_t)row * Hsz + col] = acc[mf][nf][j] + bv;
            }
    }
}

// ===========================================================================
// Fallback fp32 GEMM (only if d_ws too small for bf16x3 path)
// ===========================================================================
#define BM 128
#define BN 128
#define BK 16
#define LDSA (BM + 4)
#define LDSB (BN + 4)
__global__ __launch_bounds__(256) void sgemm_currents(
    const float* __restrict__ A, const float* __restrict__ B,
    const float* __restrict__ bias, float* __restrict__ C)
{
    __shared__ float As[BK][LDSA];
    __shared__ float Bs[BK][LDSB];
    const int tid = threadIdx.x;
    const int tx = tid & 15, ty = tid >> 4;
    const int m0 = blockIdx.y * BM, n0 = blockIdx.x * BN;
    const int arow = tid >> 2, ac4 = (tid & 3) * 4;
    const int brow = tid >> 5, bc4 = (tid & 31) * 4;
    float acc[8][8];
#pragma unroll
    for (int i = 0; i < 8; ++i)
#pragma unroll
        for (int j = 0; j < 8; ++j) acc[i][j] = 0.f;
    const float* Abase = A + (size_t)(m0 + arow) * Din + ac4;
    const float* Bbase = B + (size_t)brow * Hsz + n0 + bc4;
    float4 a0 = *(const float4*)Abase;
    float4 a1 = *(const float4*)(Abase + (size_t)64 * Din);
    float4 b0 = *(const float4*)Bbase;
    float4 b1 = *(const float4*)(Bbase + (size_t)8 * Hsz);
    const int NKT = Din / BK;
    for (int kt = 0; kt < NKT; ++kt) {
        const float* apf = (const float*)&a0;
        const float* aqf = (const float*)&a1;
#pragma unroll
        for (int j = 0; j < 4; ++j) As[ac4 + j][arow] = apf[j];
#pragma unroll
        for (int j = 0; j < 4; ++j) As[ac4 + j][arow + 64] = aqf[j];
        *(float4*)&Bs[brow][bc4] = b0;
        *(float4*)&Bs[brow + 8][bc4] = b1;
        __syncthreads();
        if (kt + 1 < NKT) {
            const float* An = Abase + (kt + 1) * BK;
            const float* Bn = Bbase + (size_t)(kt + 1) * BK * Hsz;
            a0 = *(const float4*)An;
            a1 = *(const float4*)(An + (size_t)64 * Din);
            b0 = *(const float4*)Bn;
            b1 = *(const float4*)(Bn + (size_t)8 * Hsz);
        }
#pragma unroll
        for (int k = 0; k < BK; ++k) {
            float4 af0 = *(const float4*)&As[k][ty * 8];
            float4 af1 = *(const float4*)&As[k][ty * 8 + 4];
            float4 bf0 = *(const float4*)&Bs[k][tx * 8];
            float4 bf1 = *(const float4*)&Bs[k][tx * 8 + 4];
            const float av[8] = {af0.x, af0.y, af0.z, af0.w, af1.x, af1.y, af1.z, af1.w};
            const float bv[8] = {bf0.x, bf0.y, bf0.z, bf0.w, bf1.x, bf1.y, bf1.z, bf1.w};
#pragma unroll
            for (int i = 0; i < 8; ++i)
#pragma unroll
                for (int j = 0; j < 8; ++j) acc[i][j] = fmaf(av[i], bv[j], acc[i][j]);
        }
        __syncthreads();
    }
    const float4 bi0 = *(const float4*)&bias[n0 + tx * 8];
    const float4 bi1 = *(const float4*)&bias[n0 + tx * 8 + 4];
#pragma unroll
    for (int i = 0; i < 8; ++i) {
        const size_t row = (size_t)(m0 + ty * 8 + i);
        float4 o0 = make_float4(acc[i][0] + bi0.x, acc[i][1] + bi0.y,
                                acc[i][2] + bi0.z, acc[i][3] + bi0.w);
        float4 o1 = make_float4(acc[i][4] + bi1.x, acc[i][5] + bi1.y,
                                acc[i][6] + bi1.z, acc[i][7] + bi1.w);
        float* cp = C + row * Hsz + n0 + tx * 8;
        *(float4*)cp = o0;
        *(float4*)(cp + 4) = o1;
    }
}

// ===========================================================================
// LIF step: surr = 4*e^x/(1+e^x)^2 (1 exp + 1 rcp); clamp avoids inf*0.
// ===========================================================================
__device__ __forceinline__ void lif_step(float c, float& v, float& isyn,
                                         float& so_out)
{
    constexpr float A_M  = 0.95122942450071400910f;
    constexpr float OM_M = 1.0f - A_M;
    constexpr float A_S  = 0.81873075307798182354f;
    isyn = fmaf(A_S, isyn, c);
    v    = fmaf(A_M, v, OM_M * isyn);
    const float sp = (v >= 1.0f) ? 1.0f : 0.0f;
    float x = fmaf(4.0f, v, -4.0f);
    x = fminf(x, 30.0f);
    const float ep = __expf(x);
    const float tt = 1.0f + ep;
    const float surr = 4.0f * ep * __builtin_amdgcn_rcpf(tt * tt);
    so_out = fmaf(2.0f, sp, -surr);
    v = (sp > 0.f) ? 0.0f : v;
}

// ===========================================================================
// Pass 3a: LIF scan, NON-ALIASED path. 256 blocks x 64 thr = 1 wave/CU.
// ===========================================================================
__global__ __launch_bounds__(64) void lif_scan_r(
    const float* __restrict__ cur, float* __restrict__ spikes,
    float* __restrict__ vmem, float* __restrict__ vfinal,
    float* __restrict__ partials)
{
    const int tid = threadIdx.x;
    const int gid = blockIdx.x * 64 + tid;
    const size_t base = ((size_t)(gid >> 9)) * (size_t)Tsz * Hsz + (gid & 511);

    float v = 0.f, isyn = 0.f, acc = 0.f;
    constexpr int P = 32;
    float ring[P];
#pragma unroll
    for (int p = 0; p < P; ++p) ring[p] = cur[base + (size_t)p * Hsz];

    for (int t = 0; t < Tsz; t += P) {
#pragma unroll
        for (int p = 0; p < P; ++p) {
            const float c = ring[p];
            int tn = t + P + p;
            tn = tn < (Tsz - 1) ? tn : (Tsz - 1);
            ring[p] = cur[base + (size_t)tn * Hsz];

            float so;
            lif_step(c, v, isyn, so);
            const size_t idx = base + (size_t)(t + p) * Hsz;
            __builtin_nontemporal_store(so, &spikes[idx]);
            __builtin_nontemporal_store(v,  &vmem[idx]);
            acc += so;
        }
    }
    vfinal[gid] = v;
#pragma unroll
    for (int off = 32; off; off >>= 1) acc += __shfl_down(acc, off);
    if (tid == 0) partials[blockIdx.x] = acc;
}

// ===========================================================================
// Pass 3b: LIF scan, ALIAS-SAFE fallback (cur may be the vmem region).
// ===========================================================================
__global__ __launch_bounds__(64) void lif_scan(
    const float* cur, float* spikes, float* vmem, float* vfinal, float* partials)
{
    const int tid = threadIdx.x;
    const int gid = blockIdx.x * 64 + tid;
    const size_t base = ((size_t)(gid >> 9)) * (size_t)Tsz * Hsz + (gid & 511);

    float v = 0.f, isyn = 0.f, acc = 0.f;
    constexpr int P = 8;
    float ring[P];
#pragma unroll
    for (int p = 0; p < P; ++p) ring[p] = cur[base + (size_t)p * Hsz];

    for (int t = 0; t < Tsz; t += P) {
#pragma unroll
        for (int p = 0; p < P; ++p) {
            const float c = ring[p];
            int tn = t + P + p;
            tn = tn < (Tsz - 1) ? tn : (Tsz - 1);
            ring[p] = cur[base + (size_t)tn * Hsz];

            float so;
            lif_step(c, v, isyn, so);
            const size_t idx = base + (size_t)(t + p) * Hsz;
            spikes[idx] = so;
            vmem[idx]   = v;
            acc += so;
        }
    }
    vfinal[gid] = v;
#pragma unroll
    for (int off = 32; off; off >>= 1) acc += __shfl_down(acc, off);
    if (tid == 0) partials[blockIdx.x] = acc;
}

__global__ __launch_bounds__(256) void rate_finalize(
    const float* __restrict__ partials, float* __restrict__ rate)
{
    const int tid = threadIdx.x;
    float s = partials[tid];
#pragma unroll
    for (int off = 32; off; off >>= 1) s += __shfl_down(s, off);
    __shared__ float wsum[4];
    if ((tid & 63) == 0) wsum[tid >> 6] = s;
    __syncthreads();
    if (tid == 0)
        rate[0] = ((wsum[0] + wsum[1]) + (wsum[2] + wsum[3])) * (1.0f / 16777216.0f);
}

// ===========================================================================
extern "C" void kernel_launch(void* const* d_in, const int* in_sizes, int n_in,
                              void* d_out, int out_size, void* d_ws, size_t ws_size,
                              hipStream_t stream)
{
    const float* inputs = (const float*)d_in[0];
    const float* weight = (const float*)d_in[1];
    const float* bias   = (const float*)d_in[2];

    float* out    = (float*)d_out;
    float* spikes = out;
    float* vmem   = out + ELEMS;
    float* vfinal = out + 2 * ELEMS;
    float* rate   = vfinal + (size_t)Bsz * Hsz;

    float* partials = (float*)d_ws;
    char*  ws       = (char*)d_ws;

    const size_t CUR_B = ELEMS * 4;          // 64 MiB
    const size_t ALV_B = 3 * ELEMS * 2;      // 96 MiB
    const size_t BLV_B = 3 * BELEM * 2;      // 1.5 MiB

    ushort_t *A0, *A1, *A2, *B0, *B1, *B2;
    float* cur;
    int path;
    if (ws_size >= 4096 + CUR_B + ALV_B + BLV_B) {
        cur = (float*)(ws + 4096);
        A0 = (ushort_t*)(ws + 4096 + CUR_B); A1 = A0 + ELEMS; A2 = A1 + ELEMS;
        B0 = A2 + ELEMS; B1 = B0 + BELEM; B2 = B1 + BELEM;
        path = 0;
    } else if (ws_size >= 4096 + CUR_B) {
        cur = (float*)(ws + 4096);
        A0 = (ushort_t*)d_out; A1 = A0 + ELEMS; A2 = A1 + ELEMS;
        B0 = A2 + ELEMS; B1 = B0 + BELEM; B2 = B1 + BELEM;
        path = 1;
    } else {
        cur = vmem;
        A0 = A1 = A2 = B0 = B1 = B2 = nullptr;
        path = 2;
    }

    if (path != 2) {
        split_bf16x3<<<dim3(4096 + 256), 256, 0, stream>>>(inputs, weight,
                                                           A0, A1, A2, B0, B1, B2);
        gemm_limb6<<<dim3(512), 256, 0, stream>>>(A0, A1, A2, B0, B1, B2, bias, cur);
        lif_scan_r<<<dim3(256), 64, 0, stream>>>(cur, spikes, vmem, vfinal, partials);
    } else {
        sgemm_currents<<<dim3(4, 256), 256, 0, stream>>>(inputs, weight, bias, cur);
        lif_scan<<<dim3(256), 64, 0, stream>>>(cur, spikes, vmem, vfinal, partials);
    }
    rate_finalize<<<dim3(1), 256, 0, stream>>>(partials, rate);
}

// Round 9
// 161.442 us; speedup vs baseline: 2.9439x; 1.2016x over previous
//
#include <hip/hip_runtime.h>

typedef unsigned short ushort_t;
typedef unsigned int   uint_t;
typedef float    float4v __attribute__((ext_vector_type(4)));
typedef _Float16 h16x8   __attribute__((ext_vector_type(8)));

#define Bsz 32
#define Tsz 1024
#define Din 512
#define Hsz 512
#define Mtot (Bsz * Tsz)                 // 32768
#define ELEMS ((size_t)Mtot * Hsz)       // 16777216

#define GLL16(gp, lp) __builtin_amdgcn_global_load_lds(                        \
    (const __attribute__((address_space(1))) unsigned int*)(gp),               \
    (__attribute__((address_space(3))) unsigned int*)(lp), 16, 0, 0)

// ===========================================================================
// Pass 1: exact 2-limb fp16 truncation split with power-of-2 pre-scaling.
//   A' [Mtot][1024] fp16 : [0..511] = fp16(256*x), [512..1023] = residual
//   B' [Hsz][1024] fp16  : transposed, [0..511] = fp16(2048*w), [512..]=resid
// Scales keep limb1 in fp16-normal range; epilogue multiplies by 2^-19.
// ===========================================================================
__global__ __launch_bounds__(256) void split_fp16x2(
    const float* __restrict__ A, const float* __restrict__ W,
    _Float16* __restrict__ Ah, _Float16* __restrict__ Bh)
{
    const int bid = blockIdx.x, tid = threadIdx.x;
    if (bid < 4096) {                         // A: 4096*256*16 elems = ELEMS
        const size_t e   = ((size_t)bid * 256 + tid) * 16;
        const int    row = (int)(e >> 9);
        const int    col = (int)(e & 511);
        const float4* Af = (const float4*)(A + e);
        h16x8 v0a, v1a, v0b, v1b;
#pragma unroll
        for (int q = 0; q < 4; ++q) {
            float4 x = Af[q];
            const float c[4] = {x.x, x.y, x.z, x.w};
#pragma unroll
            for (int j = 0; j < 4; ++j) {
                const float xs = c[j] * 256.0f;
                const _Float16 h0 = (_Float16)xs;
                const float rf = xs - (float)h0;     // exact
                const _Float16 h1 = (_Float16)rf;
                const int idx = q * 4 + j;
                if (idx < 8) { v0a[idx] = h0; v1a[idx] = h1; }
                else         { v0b[idx - 8] = h0; v1b[idx - 8] = h1; }
            }
        }
        _Float16* d0 = Ah + (size_t)row * 1024 + col;
        *(h16x8*)(d0)           = v0a;
        *(h16x8*)(d0 + 8)       = v0b;
        *(h16x8*)(d0 + 512)     = v1a;
        *(h16x8*)(d0 + 512 + 8) = v1b;
    } else {                                  // W split + transpose (1 MiB)
        const int f4 = (bid - 4096) * 256 + tid;
        const int k  = f4 >> 7;
        const int n4 = (f4 & 127) << 2;
        float4 x = *(const float4*)(W + (size_t)k * Hsz + n4);
        const float c[4] = {x.x, x.y, x.z, x.w};
#pragma unroll
        for (int j = 0; j < 4; ++j) {
            const float ws = c[j] * 2048.0f;
            const _Float16 h0 = (_Float16)ws;
            const float rf = ws - (float)h0;
            const _Float16 h1 = (_Float16)rf;
            _Float16* d = Bh + (size_t)(n4 + j) * 1024 + k;
            d[0]   = h0;
            d[512] = h1;
        }
    }
}

// ===========================================================================
// Pass 2: fp16 2-limb 3-product MFMA GEMM (A0B0 + A0B1 + A1B0) * 2^-19.
// 256x128 tile, 4 waves (2Mx2N, per-wave 128x64), BK=32, 16 groups x 3
// phases. bf0 register-held j0->j2; af once per limb. LDS 64 KiB.
// Uniform 4 GLL16/phase -> uniform vmcnt(4) gates.
// Byte geometry: row 2048 B | limb +1024 B | K-chunk 64 B | 64-row H 131072 B.
// R8 bugfix: B-ring staging condition k<14 (was k<13, which left B[15]
// unstaged — peeled block read stale B[13] -> last-K-window corruption).
// ===========================================================================
#define SA_STAGE(LIMB, KK, SLOTBASE) do {                                      \
    const char* g_ = Ag + (size_t)((LIMB) * 1024) + (size_t)((KK) * 64);       \
    _Pragma("unroll") for (int H = 0; H < 4; ++H)                              \
        GLL16(g_ + (size_t)H * 131072, ldsA + (SLOTBASE) + H * 4096 + lsd);    \
} while (0)

#define SB_STAGE(LIMB, KK, SLOT) do {                                          \
    const char* g_ = Bg + (size_t)((LIMB) * 1024) + (size_t)((KK) * 64);       \
    _Pragma("unroll") for (int H = 0; H < 2; ++H)                              \
        GLL16(g_ + (size_t)H * 131072, ldsB + (SLOT) * 8192 + H * 4096 + lsd); \
} while (0)

#define LD_AF(SLOTBASE) do {                                                   \
    _Pragma("unroll") for (int mf = 0; mf < 8; ++mf)                           \
        af[mf] = *(const h16x8*)(ldsA + (SLOTBASE) + (wm + mf * 16 + lr) * 64  \
                                 + physf * 16);                                \
} while (0)

#define LD_BF(DST, SLOT) do {                                                  \
    _Pragma("unroll") for (int nf = 0; nf < 4; ++nf)                           \
        DST[nf] = *(const h16x8*)(ldsB + (SLOT) * 8192 + (wn + nf * 16 + lr)   \
                                  * 64 + physf * 16);                          \
} while (0)

#define MFMAH(BF) do { __builtin_amdgcn_s_setprio(1);                          \
    _Pragma("unroll") for (int mf = 0; mf < 8; ++mf)                           \
    _Pragma("unroll") for (int nf = 0; nf < 4; ++nf)                           \
        acc[mf][nf] = __builtin_amdgcn_mfma_f32_16x16x32_f16(                  \
            af[mf], BF[nf], acc[mf][nf], 0, 0, 0);                             \
    __builtin_amdgcn_s_setprio(0); } while (0)

#define GATE(N) do { asm volatile("s_waitcnt vmcnt(" #N ")" ::: "memory");     \
    __builtin_amdgcn_sched_barrier(0); __builtin_amdgcn_s_barrier();           \
    asm volatile("" ::: "memory"); } while (0)

__global__ __launch_bounds__(256, 2) void gemm_f16k3(
    const _Float16* __restrict__ Ah, const _Float16* __restrict__ Bh,
    const float* __restrict__ bias, float* __restrict__ C)
{
    __shared__ __align__(16) char lds[65536];
    char* ldsA = lds;                 // A0 @0 (16K), A1 @16384 (16K)
    char* ldsB = lds + 32768;         // 4 x 8K B ring

    const int tid = threadIdx.x;
    const int bid = blockIdx.x;
    // XCD-bijective swizzle (nwg=512, %8==0)
    const int lin = ((bid & 7) << 6) | (bid >> 3);
    const int m0  = (lin >> 2) << 8;          // 128 m-panels x 256
    const int n0  = (lin & 3) << 7;           // 4 n-panels x 128
    const int w = tid >> 6, lane = tid & 63;
    const int wm = (w & 1) << 7;              // 0 / 128
    const int wn = (w >> 1) << 6;             // 0 / 64
    const int lr = lane & 15, lg = lane >> 4;

    const int physf = lg ^ (lr & 3) ^ ((lr >> 2) & 3);

    const int srow = tid >> 2;
    const int schk = tid & 3;
    const int logchk = schk ^ (srow & 3) ^ ((srow >> 2) & 3);
    const int lsd = tid * 16;
    const char* Ag = (const char*)Ah + (size_t)(m0 + srow) * 2048 + logchk * 16;
    const char* Bg = (const char*)Bh + (size_t)(n0 + srow) * 2048 + logchk * 16;

    float4v acc[8][4];
#pragma unroll
    for (int i = 0; i < 8; ++i)
#pragma unroll
        for (int j = 0; j < 4; ++j) acc[i][j] = (float4v)0.f;

    h16x8 af[8], bf0[4], bf1[4];

    // prologue: A0[0] -> slotA0; B0[0],B1[0],B0[1],B1[1] -> slots 0..3
    SA_STAGE(0, 0, 0);
    SB_STAGE(0, 0, 0); SB_STAGE(1, 0, 1);
    SB_STAGE(0, 1, 2); SB_STAGE(1, 1, 3);
    GATE(0);

#pragma unroll 1
    for (int k = 0; k < 15; ++k) {
        const int s0 = (2 * k) & 3, s1 = (2 * k + 1) & 3;
        // j0: (A0,B0[k]) ; stage A1[k] (read at j2, +2 gates)
        GATE(4);
        LD_AF(0); LD_BF(bf0, s0);
        SA_STAGE(1, k, 16384);
        MFMAH(bf0);
        // j1: (A0,B1[k]) ; stage A0[k+1] (read next j0, +2 gates)
        GATE(4);
        LD_BF(bf1, s1);
        SA_STAGE(0, k + 1, 0);
        MFMAH(bf1);
        // j2: (A1,B0[k]) reg-reused bf0 ; stage B[k+2] (read +4 gates)
        GATE(4);
        LD_AF(16384);
        if (k < 14) { SB_STAGE(0, k + 2, s0); SB_STAGE(1, k + 2, s1); }
        MFMAH(bf0);
    }
    {   // peeled k=15: B[15] in slots 2,3 (staged at k=13 j2)
        GATE(0);                       // drain: A0[15] staged at k14-j1
        LD_AF(0); LD_BF(bf0, 2);
        SA_STAGE(1, 15, 16384);
        MFMAH(bf0);
        GATE(4);                       // barrier only (A1[15] still in flight)
        LD_BF(bf1, 3);
        MFMAH(bf1);
        GATE(0);                       // drain: A1[15]
        LD_AF(16384);
        MFMAH(bf0);
    }

    // epilogue: undo 2^19 scaling (exact), add bias.
    // C/D map (verified R2-R6): col side = lr, row side = lg*4+j
    constexpr float INVS = 1.0f / 524288.0f;
#pragma unroll
    for (int nf = 0; nf < 4; ++nf) {
        const int col = n0 + wn + nf * 16 + lr;
        const float bv = bias[col];
#pragma unroll
        for (int mf = 0; mf < 8; ++mf)
#pragma unroll
            for (int j = 0; j < 4; ++j) {
                const int row = m0 + wm + mf * 16 + lg * 4 + j;
                C[(size_t)row * Hsz + col] = fmaf(acc[mf][nf][j], INVS, bv);
            }
    }
}

// ===========================================================================
// Fallback fp32 GEMM (only if d_ws too small)
// ===========================================================================
#define BM 128
#define BN 128
#define BK 16
#define LDSA (BM + 4)
#define LDSB (BN + 4)
__global__ __launch_bounds__(256) void sgemm_currents(
    const float* __restrict__ A, const float* __restrict__ B,
    const float* __restrict__ bias, float* __restrict__ C)
{
    __shared__ float As[BK][LDSA];
    __shared__ float Bs[BK][LDSB];
    const int tid = threadIdx.x;
    const int tx = tid & 15, ty = tid >> 4;
    const int m0 = blockIdx.y * BM, n0 = blockIdx.x * BN;
    const int arow = tid >> 2, ac4 = (tid & 3) * 4;
    const int brow = tid >> 5, bc4 = (tid & 31) * 4;
    float acc[8][8];
#pragma unroll
    for (int i = 0; i < 8; ++i)
#pragma unroll
        for (int j = 0; j < 8; ++j) acc[i][j] = 0.f;
    const float* Abase = A + (size_t)(m0 + arow) * Din + ac4;
    const float* Bbase = B + (size_t)brow * Hsz + n0 + bc4;
    float4 a0 = *(const float4*)Abase;
    float4 a1 = *(const float4*)(Abase + (size_t)64 * Din);
    float4 b0 = *(const float4*)Bbase;
    float4 b1 = *(const float4*)(Bbase + (size_t)8 * Hsz);
    const int NKT = Din / BK;
    for (int kt = 0; kt < NKT; ++kt) {
        const float* apf = (const float*)&a0;
        const float* aqf = (const float*)&a1;
#pragma unroll
        for (int j = 0; j < 4; ++j) As[ac4 + j][arow] = apf[j];
#pragma unroll
        for (int j = 0; j < 4; ++j) As[ac4 + j][arow + 64] = aqf[j];
        *(float4*)&Bs[brow][bc4] = b0;
        *(float4*)&Bs[brow + 8][bc4] = b1;
        __syncthreads();
        if (kt + 1 < NKT) {
            const float* An = Abase + (kt + 1) * BK;
            const float* Bn = Bbase + (size_t)(kt + 1) * BK * Hsz;
            a0 = *(const float4*)An;
            a1 = *(const float4*)(An + (size_t)64 * Din);
            b0 = *(const float4*)Bn;
            b1 = *(const float4*)(Bn + (size_t)8 * Hsz);
        }
#pragma unroll
        for (int k = 0; k < BK; ++k) {
            float4 af0 = *(const float4*)&As[k][ty * 8];
            float4 af1 = *(const float4*)&As[k][ty * 8 + 4];
            float4 bf0 = *(const float4*)&Bs[k][tx * 8];
            float4 bf1 = *(const float4*)&Bs[k][tx * 8 + 4];
            const float av[8] = {af0.x, af0.y, af0.z, af0.w, af1.x, af1.y, af1.z, af1.w};
            const float bv[8] = {bf0.x, bf0.y, bf0.z, bf0.w, bf1.x, bf1.y, bf1.z, bf1.w};
#pragma unroll
            for (int i = 0; i < 8; ++i)
#pragma unroll
                for (int j = 0; j < 8; ++j) acc[i][j] = fmaf(av[i], bv[j], acc[i][j]);
        }
        __syncthreads();
    }
    const float4 bi0 = *(const float4*)&bias[n0 + tx * 8];
    const float4 bi1 = *(const float4*)&bias[n0 + tx * 8 + 4];
#pragma unroll
    for (int i = 0; i < 8; ++i) {
        const size_t row = (size_t)(m0 + ty * 8 + i);
        float4 o0 = make_float4(acc[i][0] + bi0.x, acc[i][1] + bi0.y,
                                acc[i][2] + bi0.z, acc[i][3] + bi0.w);
        float4 o1 = make_float4(acc[i][4] + bi1.x, acc[i][5] + bi1.y,
                                acc[i][6] + bi1.z, acc[i][7] + bi1.w);
        float* cp = C + row * Hsz + n0 + tx * 8;
        *(float4*)cp = o0;
        *(float4*)(cp + 4) = o1;
    }
}

// ===========================================================================
// LIF step: surr = 4*e^x/(1+e^x)^2 (1 exp + 1 rcp); clamp avoids inf*0.
// ===========================================================================
__device__ __forceinline__ void lif_step(float c, float& v, float& isyn,
                                         float& so_out)
{
    constexpr float A_M  = 0.95122942450071400910f;
    constexpr float OM_M = 1.0f - A_M;
    constexpr float A_S  = 0.81873075307798182354f;
    isyn = fmaf(A_S, isyn, c);
    v    = fmaf(A_M, v, OM_M * isyn);
    const float sp = (v >= 1.0f) ? 1.0f : 0.0f;
    float x = fmaf(4.0f, v, -4.0f);
    x = fminf(x, 30.0f);
    const float ep = __expf(x);
    const float tt = 1.0f + ep;
    const float surr = 4.0f * ep * __builtin_amdgcn_rcpf(tt * tt);
    so_out = fmaf(2.0f, sp, -surr);
    v = (sp > 0.f) ? 0.0f : v;
}

// ===========================================================================
// Pass 3a: LIF scan, NON-ALIASED path. 256 blocks x 64 thr = 1 wave/CU.
// ===========================================================================
__global__ __launch_bounds__(64) void lif_scan_r(
    const float* __restrict__ cur, float* __restrict__ spikes,
    float* __restrict__ vmem, float* __restrict__ vfinal,
    float* __restrict__ partials)
{
    const int tid = threadIdx.x;
    const int gid = blockIdx.x * 64 + tid;
    const size_t base = ((size_t)(gid >> 9)) * (size_t)Tsz * Hsz + (gid & 511);

    float v = 0.f, isyn = 0.f, acc = 0.f;
    constexpr int P = 32;
    float ring[P];
#pragma unroll
    for (int p = 0; p < P; ++p) ring[p] = cur[base + (size_t)p * Hsz];

    for (int t = 0; t < Tsz; t += P) {
#pragma unroll
        for (int p = 0; p < P; ++p) {
            const float c = ring[p];
            int tn = t + P + p;
            tn = tn < (Tsz - 1) ? tn : (Tsz - 1);
            ring[p] = cur[base + (size_t)tn * Hsz];

            float so;
            lif_step(c, v, isyn, so);
            const size_t idx = base + (size_t)(t + p) * Hsz;
            __builtin_nontemporal_store(so, &spikes[idx]);
            __builtin_nontemporal_store(v,  &vmem[idx]);
            acc += so;
        }
    }
    vfinal[gid] = v;
#pragma unroll
    for (int off = 32; off; off >>= 1) acc += __shfl_down(acc, off);
    if (tid == 0) partials[blockIdx.x] = acc;
}

// ===========================================================================
// Pass 3b: LIF scan, ALIAS-SAFE fallback (cur may be the vmem region).
// ===========================================================================
__global__ __launch_bounds__(64) void lif_scan(
    const float* cur, float* spikes, float* vmem, float* vfinal, float* partials)
{
    const int tid = threadIdx.x;
    const int gid = blockIdx.x * 64 + tid;
    const size_t base = ((size_t)(gid >> 9)) * (size_t)Tsz * Hsz + (gid & 511);

    float v = 0.f, isyn = 0.f, acc = 0.f;
    constexpr int P = 8;
    float ring[P];
#pragma unroll
    for (int p = 0; p < P; ++p) ring[p] = cur[base + (size_t)p * Hsz];

    for (int t = 0; t < Tsz; t += P) {
#pragma unroll
        for (int p = 0; p < P; ++p) {
            const float c = ring[p];
            int tn = t + P + p;
            tn = tn < (Tsz - 1) ? tn : (Tsz - 1);
            ring[p] = cur[base + (size_t)tn * Hsz];

            float so;
            lif_step(c, v, isyn, so);
            const size_t idx = base + (size_t)(t + p) * Hsz;
            spikes[idx] = so;
            vmem[idx]   = v;
            acc += so;
        }
    }
    vfinal[gid] = v;
#pragma unroll
    for (int off = 32; off; off >>= 1) acc += __shfl_down(acc, off);
    if (tid == 0) partials[blockIdx.x] = acc;
}

__global__ __launch_bounds__(256) void rate_finalize(
    const float* __restrict__ partials, float* __restrict__ rate)
{
    const int tid = threadIdx.x;
    float s = partials[tid];
#pragma unroll
    for (int off = 32; off; off >>= 1) s += __shfl_down(s, off);
    __shared__ float wsum[4];
    if ((tid & 63) == 0) wsum[tid >> 6] = s;
    __syncthreads();
    if (tid == 0)
        rate[0] = ((wsum[0] + wsum[1]) + (wsum[2] + wsum[3])) * (1.0f / 16777216.0f);
}

// ===========================================================================
extern "C" void kernel_launch(void* const* d_in, const int* in_sizes, int n_in,
                              void* d_out, int out_size, void* d_ws, size_t ws_size,
                              hipStream_t stream)
{
    const float* inputs = (const float*)d_in[0];
    const float* weight = (const float*)d_in[1];
    const float* bias   = (const float*)d_in[2];

    float* out    = (float*)d_out;
    float* spikes = out;
    float* vmem   = out + ELEMS;
    float* vfinal = out + 2 * ELEMS;
    float* rate   = vfinal + (size_t)Bsz * Hsz;

    float* partials = (float*)d_ws;
    char*  ws       = (char*)d_ws;

    const size_t CUR_B = ELEMS * 4;                  // 64 MiB
    const size_t AH_B  = (size_t)Mtot * 1024 * 2;    // 64 MiB (2 fp16 limbs)
    const size_t BH_B  = (size_t)Hsz * 1024 * 2;     // 1 MiB

    _Float16 *Ah, *Bh;
    float* cur;
    int path;
    if (ws_size >= 4096 + CUR_B + AH_B + BH_B) {
        cur = (float*)(ws + 4096);
        Ah  = (_Float16*)(ws + 4096 + CUR_B);
        Bh  = Ah + (size_t)Mtot * 1024;
        path = 0;
    } else if (ws_size >= 4096 + CUR_B) {
        cur = (float*)(ws + 4096);
        Ah  = (_Float16*)d_out;                      // 65 MiB of 128 MiB out
        Bh  = Ah + (size_t)Mtot * 1024;              // scan overwrites later
        path = 1;
    } else {
        cur = vmem;
        Ah = Bh = nullptr;
        path = 2;
    }

    if (path != 2) {
        split_fp16x2<<<dim3(4096 + 256), 256, 0, stream>>>(inputs, weight, Ah, Bh);
        gemm_f16k3<<<dim3(512), 256, 0, stream>>>(Ah, Bh, bias, cur);
        lif_scan_r<<<dim3(256), 64, 0, stream>>>(cur, spikes, vmem, vfinal, partials);
    } else {
        sgemm_currents<<<dim3(4, 256), 256, 0, stream>>>(inputs, weight, bias, cur);
        lif_scan<<<dim3(256), 64, 0, stream>>>(cur, spikes, vmem, vfinal, partials);
    }
    rate_finalize<<<dim3(1), 256, 0, stream>>>(partials, rate);
}

// Round 10
// 161.024 us; speedup vs baseline: 2.9515x; 1.0026x over previous
//
#include <hip/hip_runtime.h>

typedef unsigned short ushort_t;
typedef unsigned int   uint_t;
typedef float    float4v __attribute__((ext_vector_type(4)));
typedef _Float16 h16x8   __attribute__((ext_vector_type(8)));

#define Bsz 32
#define Tsz 1024
#define Din 512
#define Hsz 512
#define Mtot (Bsz * Tsz)                 // 32768
#define ELEMS ((size_t)Mtot * Hsz)       // 16777216

#define GLL16(gp, lp) __builtin_amdgcn_global_load_lds(                        \
    (const __attribute__((address_space(1))) unsigned int*)(gp),               \
    (__attribute__((address_space(3))) unsigned int*)(lp), 16, 0, 0)

// ===========================================================================
// Pass 1: exact 2-limb fp16 truncation split with power-of-2 pre-scaling.
//   A' [Mtot][1024] fp16 : [0..511] = fp16(256*x), [512..1023] = residual
//   B' [Hsz][1024] fp16  : transposed, [0..511] = fp16(2048*w), [512..]=resid
// ===========================================================================
__global__ __launch_bounds__(256) void split_fp16x2(
    const float* __restrict__ A, const float* __restrict__ W,
    _Float16* __restrict__ Ah, _Float16* __restrict__ Bh)
{
    const int bid = blockIdx.x, tid = threadIdx.x;
    if (bid < 4096) {                         // A: 4096*256*16 elems = ELEMS
        const size_t e   = ((size_t)bid * 256 + tid) * 16;
        const int    row = (int)(e >> 9);
        const int    col = (int)(e & 511);
        const float4* Af = (const float4*)(A + e);
        h16x8 v0a, v1a, v0b, v1b;
#pragma unroll
        for (int q = 0; q < 4; ++q) {
            float4 x = Af[q];
            const float c[4] = {x.x, x.y, x.z, x.w};
#pragma unroll
            for (int j = 0; j < 4; ++j) {
                const float xs = c[j] * 256.0f;
                const _Float16 h0 = (_Float16)xs;
                const float rf = xs - (float)h0;     // exact
                const _Float16 h1 = (_Float16)rf;
                const int idx = q * 4 + j;
                if (idx < 8) { v0a[idx] = h0; v1a[idx] = h1; }
                else         { v0b[idx - 8] = h0; v1b[idx - 8] = h1; }
            }
        }
        _Float16* d0 = Ah + (size_t)row * 1024 + col;
        *(h16x8*)(d0)           = v0a;
        *(h16x8*)(d0 + 8)       = v0b;
        *(h16x8*)(d0 + 512)     = v1a;
        *(h16x8*)(d0 + 512 + 8) = v1b;
    } else {                                  // W split + transpose (1 MiB)
        const int f4 = (bid - 4096) * 256 + tid;
        const int k  = f4 >> 7;
        const int n4 = (f4 & 127) << 2;
        float4 x = *(const float4*)(W + (size_t)k * Hsz + n4);
        const float c[4] = {x.x, x.y, x.z, x.w};
#pragma unroll
        for (int j = 0; j < 4; ++j) {
            const float ws = c[j] * 2048.0f;
            const _Float16 h0 = (_Float16)ws;
            const float rf = ws - (float)h0;
            const _Float16 h1 = (_Float16)rf;
            _Float16* d = Bh + (size_t)(n4 + j) * 1024 + k;
            d[0]   = h0;
            d[512] = h1;
        }
    }
}

// ===========================================================================
// Pass 2: fp16 2-limb 3-product MFMA GEMM (A0B0 + A0B1 + A1B0) * 2^-19.
// (unchanged from R9 — verified passing)
// ===========================================================================
#define SA_STAGE(LIMB, KK, SLOTBASE) do {                                      \
    const char* g_ = Ag + (size_t)((LIMB) * 1024) + (size_t)((KK) * 64);       \
    _Pragma("unroll") for (int H = 0; H < 4; ++H)                              \
        GLL16(g_ + (size_t)H * 131072, ldsA + (SLOTBASE) + H * 4096 + lsd);    \
} while (0)

#define SB_STAGE(LIMB, KK, SLOT) do {                                          \
    const char* g_ = Bg + (size_t)((LIMB) * 1024) + (size_t)((KK) * 64);       \
    _Pragma("unroll") for (int H = 0; H < 2; ++H)                              \
        GLL16(g_ + (size_t)H * 131072, ldsB + (SLOT) * 8192 + H * 4096 + lsd); \
} while (0)

#define LD_AF(SLOTBASE) do {                                                   \
    _Pragma("unroll") for (int mf = 0; mf < 8; ++mf)                           \
        af[mf] = *(const h16x8*)(ldsA + (SLOTBASE) + (wm + mf * 16 + lr) * 64  \
                                 + physf * 16);                                \
} while (0)

#define LD_BF(DST, SLOT) do {                                                  \
    _Pragma("unroll") for (int nf = 0; nf < 4; ++nf)                           \
        DST[nf] = *(const h16x8*)(ldsB + (SLOT) * 8192 + (wn + nf * 16 + lr)   \
                                  * 64 + physf * 16);                          \
} while (0)

#define MFMAH(BF) do { __builtin_amdgcn_s_setprio(1);                          \
    _Pragma("unroll") for (int mf = 0; mf < 8; ++mf)                           \
    _Pragma("unroll") for (int nf = 0; nf < 4; ++nf)                           \
        acc[mf][nf] = __builtin_amdgcn_mfma_f32_16x16x32_f16(                  \
            af[mf], BF[nf], acc[mf][nf], 0, 0, 0);                             \
    __builtin_amdgcn_s_setprio(0); } while (0)

#define GATE(N) do { asm volatile("s_waitcnt vmcnt(" #N ")" ::: "memory");     \
    __builtin_amdgcn_sched_barrier(0); __builtin_amdgcn_s_barrier();           \
    asm volatile("" ::: "memory"); } while (0)

__global__ __launch_bounds__(256, 2) void gemm_f16k3(
    const _Float16* __restrict__ Ah, const _Float16* __restrict__ Bh,
    const float* __restrict__ bias, float* __restrict__ C)
{
    __shared__ __align__(16) char lds[65536];
    char* ldsA = lds;                 // A0 @0 (16K), A1 @16384 (16K)
    char* ldsB = lds + 32768;         // 4 x 8K B ring

    const int tid = threadIdx.x;
    const int bid = blockIdx.x;
    const int lin = ((bid & 7) << 6) | (bid >> 3);
    const int m0  = (lin >> 2) << 8;
    const int n0  = (lin & 3) << 7;
    const int w = tid >> 6, lane = tid & 63;
    const int wm = (w & 1) << 7;
    const int wn = (w >> 1) << 6;
    const int lr = lane & 15, lg = lane >> 4;

    const int physf = lg ^ (lr & 3) ^ ((lr >> 2) & 3);

    const int srow = tid >> 2;
    const int schk = tid & 3;
    const int logchk = schk ^ (srow & 3) ^ ((srow >> 2) & 3);
    const int lsd = tid * 16;
    const char* Ag = (const char*)Ah + (size_t)(m0 + srow) * 2048 + logchk * 16;
    const char* Bg = (const char*)Bh + (size_t)(n0 + srow) * 2048 + logchk * 16;

    float4v acc[8][4];
#pragma unroll
    for (int i = 0; i < 8; ++i)
#pragma unroll
        for (int j = 0; j < 4; ++j) acc[i][j] = (float4v)0.f;

    h16x8 af[8], bf0[4], bf1[4];

    SA_STAGE(0, 0, 0);
    SB_STAGE(0, 0, 0); SB_STAGE(1, 0, 1);
    SB_STAGE(0, 1, 2); SB_STAGE(1, 1, 3);
    GATE(0);

#pragma unroll 1
    for (int k = 0; k < 15; ++k) {
        const int s0 = (2 * k) & 3, s1 = (2 * k + 1) & 3;
        GATE(4);
        LD_AF(0); LD_BF(bf0, s0);
        SA_STAGE(1, k, 16384);
        MFMAH(bf0);
        GATE(4);
        LD_BF(bf1, s1);
        SA_STAGE(0, k + 1, 0);
        MFMAH(bf1);
        GATE(4);
        LD_AF(16384);
        if (k < 14) { SB_STAGE(0, k + 2, s0); SB_STAGE(1, k + 2, s1); }
        MFMAH(bf0);
    }
    {   // peeled k=15: B[15] in slots 2,3 (staged at k=13 j2)
        GATE(0);
        LD_AF(0); LD_BF(bf0, 2);
        SA_STAGE(1, 15, 16384);
        MFMAH(bf0);
        GATE(4);
        LD_BF(bf1, 3);
        MFMAH(bf1);
        GATE(0);
        LD_AF(16384);
        MFMAH(bf0);
    }

    constexpr float INVS = 1.0f / 524288.0f;
#pragma unroll
    for (int nf = 0; nf < 4; ++nf) {
        const int col = n0 + wn + nf * 16 + lr;
        const float bv = bias[col];
#pragma unroll
        for (int mf = 0; mf < 8; ++mf)
#pragma unroll
            for (int j = 0; j < 4; ++j) {
                const int row = m0 + wm + mf * 16 + lg * 4 + j;
                C[(size_t)row * Hsz + col] = fmaf(acc[mf][nf][j], INVS, bv);
            }
    }
}

// ===========================================================================
// Fallback fp32 GEMM (only if d_ws too small)
// ===========================================================================
#define BM 128
#define BN 128
#define BK 16
#define LDSA (BM + 4)
#define LDSB (BN + 4)
__global__ __launch_bounds__(256) void sgemm_currents(
    const float* __restrict__ A, const float* __restrict__ B,
    const float* __restrict__ bias, float* __restrict__ C)
{
    __shared__ float As[BK][LDSA];
    __shared__ float Bs[BK][LDSB];
    const int tid = threadIdx.x;
    const int tx = tid & 15, ty = tid >> 4;
    const int m0 = blockIdx.y * BM, n0 = blockIdx.x * BN;
    const int arow = tid >> 2, ac4 = (tid & 3) * 4;
    const int brow = tid >> 5, bc4 = (tid & 31) * 4;
    float acc[8][8];
#pragma unroll
    for (int i = 0; i < 8; ++i)
#pragma unroll
        for (int j = 0; j < 8; ++j) acc[i][j] = 0.f;
    const float* Abase = A + (size_t)(m0 + arow) * Din + ac4;
    const float* Bbase = B + (size_t)brow * Hsz + n0 + bc4;
    float4 a0 = *(const float4*)Abase;
    float4 a1 = *(const float4*)(Abase + (size_t)64 * Din);
    float4 b0 = *(const float4*)Bbase;
    float4 b1 = *(const float4*)(Bbase + (size_t)8 * Hsz);
    const int NKT = Din / BK;
    for (int kt = 0; kt < NKT; ++kt) {
        const float* apf = (const float*)&a0;
        const float* aqf = (const float*)&a1;
#pragma unroll
        for (int j = 0; j < 4; ++j) As[ac4 + j][arow] = apf[j];
#pragma unroll
        for (int j = 0; j < 4; ++j) As[ac4 + j][arow + 64] = aqf[j];
        *(float4*)&Bs[brow][bc4] = b0;
        *(float4*)&Bs[brow + 8][bc4] = b1;
        __syncthreads();
        if (kt + 1 < NKT) {
            const float* An = Abase + (kt + 1) * BK;
            const float* Bn = Bbase + (size_t)(kt + 1) * BK * Hsz;
            a0 = *(const float4*)An;
            a1 = *(const float4*)(An + (size_t)64 * Din);
            b0 = *(const float4*)Bn;
            b1 = *(const float4*)(Bn + (size_t)8 * Hsz);
        }
#pragma unroll
        for (int k = 0; k < BK; ++k) {
            float4 af0 = *(const float4*)&As[k][ty * 8];
            float4 af1 = *(const float4*)&As[k][ty * 8 + 4];
            float4 bf0 = *(const float4*)&Bs[k][tx * 8];
            float4 bf1 = *(const float4*)&Bs[k][tx * 8 + 4];
            const float av[8] = {af0.x, af0.y, af0.z, af0.w, af1.x, af1.y, af1.z, af1.w};
            const float bv[8] = {bf0.x, bf0.y, bf0.z, bf0.w, bf1.x, bf1.y, bf1.z, bf1.w};
#pragma unroll
            for (int i = 0; i < 8; ++i)
#pragma unroll
                for (int j = 0; j < 8; ++j) acc[i][j] = fmaf(av[i], bv[j], acc[i][j]);
        }
        __syncthreads();
    }
    const float4 bi0 = *(const float4*)&bias[n0 + tx * 8];
    const float4 bi1 = *(const float4*)&bias[n0 + tx * 8 + 4];
#pragma unroll
    for (int i = 0; i < 8; ++i) {
        const size_t row = (size_t)(m0 + ty * 8 + i);
        float4 o0 = make_float4(acc[i][0] + bi0.x, acc[i][1] + bi0.y,
                                acc[i][2] + bi0.z, acc[i][3] + bi0.w);
        float4 o1 = make_float4(acc[i][4] + bi1.x, acc[i][5] + bi1.y,
                                acc[i][6] + bi1.z, acc[i][7] + bi1.w);
        float* cp = C + row * Hsz + n0 + tx * 8;
        *(float4*)cp = o0;
        *(float4*)(cp + 4) = o1;
    }
}

// ===========================================================================
// Pass 3a: LIF scan v2 (non-aliased). 256 blocks x 64 thr = 1 wave/CU.
// R9 fix: PLAIN stores (NT stores clogged the 63-deep in-order vmcnt queue
// with HBM-latency completions -> wave stalled ~41cyc/step on ring waits).
// P=16 ring: reuse distance 47 vmem ops < 63 -> exact counted waits.
// Shared 32-bit voffset (one +2048/step) serves cur (pre-biased base +32KB),
// spikes and vmem. Last 16 steps peeled (no prefetch -> no OOB past cur).
// ===========================================================================
#define LSTEP(PP, PRE) do {                                                    \
    const float c = ring[PP];                                                  \
    if (PRE) ring[PP] = *(const float*)(curp2 + off);                          \
    isyn = fmaf(A_S, isyn, c);                                                 \
    v    = fmaf(A_M, v, OM_M * isyn);                                          \
    const bool sb = (v >= 1.0f);                                               \
    float x = fmaf(4.0f, v, -4.0f);                                            \
    x = fminf(x, 30.0f);                                                       \
    const float ep = __expf(x);                                                \
    const float tt = 1.0f + ep;                                                \
    const float r  = __builtin_amdgcn_rcpf(tt * tt);                           \
    const float sp = sb ? 1.0f : 0.0f;                                         \
    const float so = fmaf(-4.0f * ep, r, sp + sp);                             \
    v = sb ? 0.0f : v;                                                         \
    acc += so;                                                                 \
    *(float*)(spkp + off) = so;                                                \
    *(float*)(vmmp + off) = v;                                                 \
    off += 2048u;                                                              \
} while (0)

__global__ __launch_bounds__(64) void lif_scan_r(
    const float* __restrict__ cur, float* __restrict__ spikes,
    float* __restrict__ vmem, float* __restrict__ vfinal,
    float* __restrict__ partials)
{
    constexpr float A_M  = 0.95122942450071400910f;
    constexpr float OM_M = 1.0f - A_M;
    constexpr float A_S  = 0.81873075307798182354f;

    const int tid = threadIdx.x;
    const int gid = blockIdx.x * 64 + tid;
    const uint_t base = ((uint_t)(gid >> 9) * (uint_t)(Tsz * Hsz) +
                         (uint_t)(gid & 511)) * 4u;          // byte offset

    const char* curp  = (const char*)cur;
    const char* curp2 = curp + 16 * 2048;     // pre-biased prefetch base
    char* spkp = (char*)spikes;
    char* vmmp = (char*)vmem;

    float v = 0.f, isyn = 0.f, acc = 0.f;
    constexpr int P = 16;
    float ring[P];
#pragma unroll
    for (int p = 0; p < P; ++p)
        ring[p] = *(const float*)(curp + base + (uint_t)(p * 2048));

    uint_t off = base;
#pragma unroll 1
    for (int t = 0; t < Tsz - P; t += P) {    // 63 iters, prefetch on
#pragma unroll
        for (int p = 0; p < P; ++p) LSTEP(p, 1);
    }
    {   // tail: last 16 steps, no prefetch
#pragma unroll
        for (int p = 0; p < P; ++p) LSTEP(p, 0);
    }

    vfinal[gid] = v;
#pragma unroll
    for (int offs = 32; offs; offs >>= 1) acc += __shfl_down(acc, offs);
    if (tid == 0) partials[blockIdx.x] = acc;
}

// ===========================================================================
// Pass 3b: LIF scan, ALIAS-SAFE fallback (cur may be the vmem region).
// ===========================================================================
__device__ __forceinline__ void lif_step(float c, float& v, float& isyn,
                                         float& so_out)
{
    constexpr float A_M  = 0.95122942450071400910f;
    constexpr float OM_M = 1.0f - A_M;
    constexpr float A_S  = 0.81873075307798182354f;
    isyn = fmaf(A_S, isyn, c);
    v    = fmaf(A_M, v, OM_M * isyn);
    const float sp = (v >= 1.0f) ? 1.0f : 0.0f;
    float x = fmaf(4.0f, v, -4.0f);
    x = fminf(x, 30.0f);
    const float ep = __expf(x);
    const float tt = 1.0f + ep;
    const float surr = 4.0f * ep * __builtin_amdgcn_rcpf(tt * tt);
    so_out = fmaf(2.0f, sp, -surr);
    v = (sp > 0.f) ? 0.0f : v;
}

__global__ __launch_bounds__(64) void lif_scan(
    const float* cur, float* spikes, float* vmem, float* vfinal, float* partials)
{
    const int tid = threadIdx.x;
    const int gid = blockIdx.x * 64 + tid;
    const size_t base = ((size_t)(gid >> 9)) * (size_t)Tsz * Hsz + (gid & 511);

    float v = 0.f, isyn = 0.f, acc = 0.f;
    constexpr int P = 8;
    float ring[P];
#pragma unroll
    for (int p = 0; p < P; ++p) ring[p] = cur[base + (size_t)p * Hsz];

    for (int t = 0; t < Tsz; t += P) {
#pragma unroll
        for (int p = 0; p < P; ++p) {
            const float c = ring[p];
            int tn = t + P + p;
            tn = tn < (Tsz - 1) ? tn : (Tsz - 1);
            ring[p] = cur[base + (size_t)tn * Hsz];

            float so;
            lif_step(c, v, isyn, so);
            const size_t idx = base + (size_t)(t + p) * Hsz;
            spikes[idx] = so;
            vmem[idx]   = v;
            acc += so;
        }
    }
    vfinal[gid] = v;
#pragma unroll
    for (int off = 32; off; off >>= 1) acc += __shfl_down(acc, off);
    if (tid == 0) partials[blockIdx.x] = acc;
}

__global__ __launch_bounds__(256) void rate_finalize(
    const float* __restrict__ partials, float* __restrict__ rate)
{
    const int tid = threadIdx.x;
    float s = partials[tid];
#pragma unroll
    for (int off = 32; off; off >>= 1) s += __shfl_down(s, off);
    __shared__ float wsum[4];
    if ((tid & 63) == 0) wsum[tid >> 6] = s;
    __syncthreads();
    if (tid == 0)
        rate[0] = ((wsum[0] + wsum[1]) + (wsum[2] + wsum[3])) * (1.0f / 16777216.0f);
}

// ===========================================================================
extern "C" void kernel_launch(void* const* d_in, const int* in_sizes, int n_in,
                              void* d_out, int out_size, void* d_ws, size_t ws_size,
                              hipStream_t stream)
{
    const float* inputs = (const float*)d_in[0];
    const float* weight = (const float*)d_in[1];
    const float* bias   = (const float*)d_in[2];

    float* out    = (float*)d_out;
    float* spikes = out;
    float* vmem   = out + ELEMS;
    float* vfinal = out + 2 * ELEMS;
    float* rate   = vfinal + (size_t)Bsz * Hsz;

    float* partials = (float*)d_ws;
    char*  ws       = (char*)d_ws;

    const size_t CUR_B = ELEMS * 4;                  // 64 MiB
    const size_t AH_B  = (size_t)Mtot * 1024 * 2;    // 64 MiB (2 fp16 limbs)
    const size_t BH_B  = (size_t)Hsz * 1024 * 2;     // 1 MiB

    _Float16 *Ah, *Bh;
    float* cur;
    int path;
    if (ws_size >= 4096 + CUR_B + AH_B + BH_B) {
        cur = (float*)(ws + 4096);
        Ah  = (_Float16*)(ws + 4096 + CUR_B);
        Bh  = Ah + (size_t)Mtot * 1024;
        path = 0;
    } else if (ws_size >= 4096 + CUR_B) {
        cur = (float*)(ws + 4096);
        Ah  = (_Float16*)d_out;                      // scan overwrites later
        Bh  = Ah + (size_t)Mtot * 1024;
        path = 1;
    } else {
        cur = vmem;
        Ah = Bh = nullptr;
        path = 2;
    }

    if (path != 2) {
        split_fp16x2<<<dim3(4096 + 256), 256, 0, stream>>>(inputs, weight, Ah, Bh);
        gemm_f16k3<<<dim3(512), 256, 0, stream>>>(Ah, Bh, bias, cur);
        lif_scan_r<<<dim3(256), 64, 0, stream>>>(cur, spikes, vmem, vfinal, partials);
    } else {
        sgemm_currents<<<dim3(4, 256), 256, 0, stream>>>(inputs, weight, bias, cur);
        lif_scan<<<dim3(256), 64, 0, stream>>>(cur, spikes, vmem, vfinal, partials);
    }
    rate_finalize<<<dim3(1), 256, 0, stream>>>(partials, rate);
}

// Round 13
// 153.865 us; speedup vs baseline: 3.0889x; 1.0465x over previous
//
#include <hip/hip_runtime.h>

typedef unsigned short ushort_t;
typedef unsigned int   uint_t;
typedef float    float4v __attribute__((ext_vector_type(4)));
typedef _Float16 h16x8   __attribute__((ext_vector_type(8)));

#define Bsz 32
#define Tsz 1024
#define Din 512
#define Hsz 512
#define Mtot (Bsz * Tsz)                 // 32768
#define ELEMS ((size_t)Mtot * Hsz)       // 16777216

#define GLL16(gp, lp) __builtin_amdgcn_global_load_lds(                        \
    (const __attribute__((address_space(1))) unsigned int*)(gp),               \
    (__attribute__((address_space(3))) unsigned int*)(lp), 16, 0, 0)

#define GLL4(gp, lp) __builtin_amdgcn_global_load_lds(                         \
    (const __attribute__((address_space(1))) unsigned int*)(gp),               \
    (__attribute__((address_space(3))) unsigned int*)(lp), 4, 0, 0)

// ===========================================================================
// Pass 1: exact 2-limb fp16 truncation split with power-of-2 pre-scaling.
//   A' [Mtot][1024] fp16 : [0..511] = fp16(256*x), [512..1023] = residual
//   B' [Hsz][1024] fp16  : transposed, [0..511] = fp16(2048*w), [512..]=resid
// ===========================================================================
__global__ __launch_bounds__(256) void split_fp16x2(
    const float* __restrict__ A, const float* __restrict__ W,
    _Float16* __restrict__ Ah, _Float16* __restrict__ Bh)
{
    const int bid = blockIdx.x, tid = threadIdx.x;
    if (bid < 4096) {                         // A: 4096*256*16 elems = ELEMS
        const size_t e   = ((size_t)bid * 256 + tid) * 16;
        const int    row = (int)(e >> 9);
        const int    col = (int)(e & 511);
        const float4* Af = (const float4*)(A + e);
        h16x8 v0a, v1a, v0b, v1b;
#pragma unroll
        for (int q = 0; q < 4; ++q) {
            float4 x = Af[q];
            const float c[4] = {x.x, x.y, x.z, x.w};
#pragma unroll
            for (int j = 0; j < 4; ++j) {
                const float xs = c[j] * 256.0f;
                const _Float16 h0 = (_Float16)xs;
                const float rf = xs - (float)h0;     // exact
                const _Float16 h1 = (_Float16)rf;
                const int idx = q * 4 + j;
                if (idx < 8) { v0a[idx] = h0; v1a[idx] = h1; }
                else         { v0b[idx - 8] = h0; v1b[idx - 8] = h1; }
            }
        }
        _Float16* d0 = Ah + (size_t)row * 1024 + col;
        *(h16x8*)(d0)           = v0a;
        *(h16x8*)(d0 + 8)       = v0b;
        *(h16x8*)(d0 + 512)     = v1a;
        *(h16x8*)(d0 + 512 + 8) = v1b;
    } else {                                  // W split + transpose (1 MiB)
        const int f4 = (bid - 4096) * 256 + tid;
        const int k  = f4 >> 7;
        const int n4 = (f4 & 127) << 2;
        float4 x = *(const float4*)(W + (size_t)k * Hsz + n4);
        const float c[4] = {x.x, x.y, x.z, x.w};
#pragma unroll
        for (int j = 0; j < 4; ++j) {
            const float ws = c[j] * 2048.0f;
            const _Float16 h0 = (_Float16)ws;
            const float rf = ws - (float)h0;
            const _Float16 h1 = (_Float16)rf;
            _Float16* d = Bh + (size_t)(n4 + j) * 1024 + k;
            d[0]   = h0;
            d[512] = h1;
        }
    }
}

// ===========================================================================
// Pass 2: fp16 2-limb 3-product MFMA GEMM (A0B0 + A0B1 + A1B0) * 2^-19.
// (byte-identical to R9/R10 — verified passing)
// ===========================================================================
#define SA_STAGE(LIMB, KK, SLOTBASE) do {                                      \
    const char* g_ = Ag + (size_t)((LIMB) * 1024) + (size_t)((KK) * 64);       \
    _Pragma("unroll") for (int H = 0; H < 4; ++H)                              \
        GLL16(g_ + (size_t)H * 131072, ldsA + (SLOTBASE) + H * 4096 + lsd);    \
} while (0)

#define SB_STAGE(LIMB, KK, SLOT) do {                                          \
    const char* g_ = Bg + (size_t)((LIMB) * 1024) + (size_t)((KK) * 64);       \
    _Pragma("unroll") for (int H = 0; H < 2; ++H)                              \
        GLL16(g_ + (size_t)H * 131072, ldsB + (SLOT) * 8192 + H * 4096 + lsd); \
} while (0)

#define LD_AF(SLOTBASE) do {                                                   \
    _Pragma("unroll") for (int mf = 0; mf < 8; ++mf)                           \
        af[mf] = *(const h16x8*)(ldsA + (SLOTBASE) + (wm + mf * 16 + lr) * 64  \
                                 + physf * 16);                                \
} while (0)

#define LD_BF(DST, SLOT) do {                                                  \
    _Pragma("unroll") for (int nf = 0; nf < 4; ++nf)                           \
        DST[nf] = *(const h16x8*)(ldsB + (SLOT) * 8192 + (wn + nf * 16 + lr)   \
                                  * 64 + physf * 16);                          \
} while (0)

#define MFMAH(BF) do { __builtin_amdgcn_s_setprio(1);                          \
    _Pragma("unroll") for (int mf = 0; mf < 8; ++mf)                           \
    _Pragma("unroll") for (int nf = 0; nf < 4; ++nf)                           \
        acc[mf][nf] = __builtin_amdgcn_mfma_f32_16x16x32_f16(                  \
            af[mf], BF[nf], acc[mf][nf], 0, 0, 0);                             \
    __builtin_amdgcn_s_setprio(0); } while (0)

#define GATE(N) do { asm volatile("s_waitcnt vmcnt(" #N ")" ::: "memory");     \
    __builtin_amdgcn_sched_barrier(0); __builtin_amdgcn_s_barrier();           \
    asm volatile("" ::: "memory"); } while (0)

__global__ __launch_bounds__(256, 2) void gemm_f16k3(
    const _Float16* __restrict__ Ah, const _Float16* __restrict__ Bh,
    const float* __restrict__ bias, float* __restrict__ C)
{
    __shared__ __align__(16) char lds[65536];
    char* ldsA = lds;                 // A0 @0 (16K), A1 @16384 (16K)
    char* ldsB = lds + 32768;         // 4 x 8K B ring

    const int tid = threadIdx.x;
    const int bid = blockIdx.x;
    const int lin = ((bid & 7) << 6) | (bid >> 3);
    const int m0  = (lin >> 2) << 8;
    const int n0  = (lin & 3) << 7;
    const int w = tid >> 6, lane = tid & 63;
    const int wm = (w & 1) << 7;
    const int wn = (w >> 1) << 6;
    const int lr = lane & 15, lg = lane >> 4;

    const int physf = lg ^ (lr & 3) ^ ((lr >> 2) & 3);

    const int srow = tid >> 2;
    const int schk = tid & 3;
    const int logchk = schk ^ (srow & 3) ^ ((srow >> 2) & 3);
    const int lsd = tid * 16;
    const char* Ag = (const char*)Ah + (size_t)(m0 + srow) * 2048 + logchk * 16;
    const char* Bg = (const char*)Bh + (size_t)(n0 + srow) * 2048 + logchk * 16;

    float4v acc[8][4];
#pragma unroll
    for (int i = 0; i < 8; ++i)
#pragma unroll
        for (int j = 0; j < 4; ++j) acc[i][j] = (float4v)0.f;

    h16x8 af[8], bf0[4], bf1[4];

    SA_STAGE(0, 0, 0);
    SB_STAGE(0, 0, 0); SB_STAGE(1, 0, 1);
    SB_STAGE(0, 1, 2); SB_STAGE(1, 1, 3);
    GATE(0);

#pragma unroll 1
    for (int k = 0; k < 15; ++k) {
        const int s0 = (2 * k) & 3, s1 = (2 * k + 1) & 3;
        GATE(4);
        LD_AF(0); LD_BF(bf0, s0);
        SA_STAGE(1, k, 16384);
        MFMAH(bf0);
        GATE(4);
        LD_BF(bf1, s1);
        SA_STAGE(0, k + 1, 0);
        MFMAH(bf1);
        GATE(4);
        LD_AF(16384);
        if (k < 14) { SB_STAGE(0, k + 2, s0); SB_STAGE(1, k + 2, s1); }
        MFMAH(bf0);
    }
    {   // peeled k=15: B[15] in slots 2,3 (staged at k=13 j2)
        GATE(0);
        LD_AF(0); LD_BF(bf0, 2);
        SA_STAGE(1, 15, 16384);
        MFMAH(bf0);
        GATE(4);
        LD_BF(bf1, 3);
        MFMAH(bf1);
        GATE(0);
        LD_AF(16384);
        MFMAH(bf0);
    }

    constexpr float INVS = 1.0f / 524288.0f;
#pragma unroll
    for (int nf = 0; nf < 4; ++nf) {
        const int col = n0 + wn + nf * 16 + lr;
        const float bv = bias[col];
#pragma unroll
        for (int mf = 0; mf < 8; ++mf)
#pragma unroll
            for (int j = 0; j < 4; ++j) {
                const int row = m0 + wm + mf * 16 + lg * 4 + j;
                C[(size_t)row * Hsz + col] = fmaf(acc[mf][nf][j], INVS, bv);
            }
    }
}

// ===========================================================================
// Fallback fp32 GEMM (only if d_ws too small)
// ===========================================================================
#define BM 128
#define BN 128
#define BK 16
#define LDSA (BM + 4)
#define LDSB (BN + 4)
__global__ __launch_bounds__(256) void sgemm_currents(
    const float* __restrict__ A, const float* __restrict__ B,
    const float* __restrict__ bias, float* __restrict__ C)
{
    __shared__ float As[BK][LDSA];
    __shared__ float Bs[BK][LDSB];
    const int tid = threadIdx.x;
    const int tx = tid & 15, ty = tid >> 4;
    const int m0 = blockIdx.y * BM, n0 = blockIdx.x * BN;
    const int arow = tid >> 2, ac4 = (tid & 3) * 4;
    const int brow = tid >> 5, bc4 = (tid & 31) * 4;
    float acc[8][8];
#pragma unroll
    for (int i = 0; i < 8; ++i)
#pragma unroll
        for (int j = 0; j < 8; ++j) acc[i][j] = 0.f;
    const float* Abase = A + (size_t)(m0 + arow) * Din + ac4;
    const float* Bbase = B + (size_t)brow * Hsz + n0 + bc4;
    float4 a0 = *(const float4*)Abase;
    float4 a1 = *(const float4*)(Abase + (size_t)64 * Din);
    float4 b0 = *(const float4*)Bbase;
    float4 b1 = *(const float4*)(Bbase + (size_t)8 * Hsz);
    const int NKT = Din / BK;
    for (int kt = 0; kt < NKT; ++kt) {
        const float* apf = (const float*)&a0;
        const float* aqf = (const float*)&a1;
#pragma unroll
        for (int j = 0; j < 4; ++j) As[ac4 + j][arow] = apf[j];
#pragma unroll
        for (int j = 0; j < 4; ++j) As[ac4 + j][arow + 64] = aqf[j];
        *(float4*)&Bs[brow][bc4] = b0;
        *(float4*)&Bs[brow + 8][bc4] = b1;
        __syncthreads();
        if (kt + 1 < NKT) {
            const float* An = Abase + (kt + 1) * BK;
            const float* Bn = Bbase + (size_t)(kt + 1) * BK * Hsz;
            a0 = *(const float4*)An;
            a1 = *(const float4*)(An + (size_t)64 * Din);
            b0 = *(const float4*)Bn;
            b1 = *(const float4*)(Bn + (size_t)8 * Hsz);
        }
#pragma unroll
        for (int k = 0; k < BK; ++k) {
            float4 af0 = *(const float4*)&As[k][ty * 8];
            float4 af1 = *(const float4*)&As[k][ty * 8 + 4];
            float4 bf0 = *(const float4*)&Bs[k][tx * 8];
            float4 bf1 = *(const float4*)&Bs[k][tx * 8 + 4];
            const float av[8] = {af0.x, af0.y, af0.z, af0.w, af1.x, af1.y, af1.z, af1.w};
            const float bv[8] = {bf0.x, bf0.y, bf0.z, bf0.w, bf1.x, bf1.y, bf1.z, bf1.w};
#pragma unroll
            for (int i = 0; i < 8; ++i)
#pragma unroll
                for (int j = 0; j < 8; ++j) acc[i][j] = fmaf(av[i], bv[j], acc[i][j]);
        }
        __syncthreads();
    }
    const float4 bi0 = *(const float4*)&bias[n0 + tx * 8];
    const float4 bi1 = *(const float4*)&bias[n0 + tx * 8 + 4];
#pragma unroll
    for (int i = 0; i < 8; ++i) {
        const size_t row = (size_t)(m0 + ty * 8 + i);
        float4 o0 = make_float4(acc[i][0] + bi0.x, acc[i][1] + bi0.y,
                                acc[i][2] + bi0.z, acc[i][3] + bi0.w);
        float4 o1 = make_float4(acc[i][4] + bi1.x, acc[i][5] + bi1.y,
                                acc[i][6] + bi1.z, acc[i][7] + bi1.w);
        float* cp = C + row * Hsz + n0 + tx * 8;
        *(float4*)cp = o0;
        *(float4*)(cp + 4) = o1;
    }
}

// ===========================================================================
// Pass 3a: LIF scan v4 (non-aliased). 256 blocks x 64 thr = 1 wave/CU.
// R11/R12 post-mortem: hand vmcnt ledger on register-destined asm loads
// aborted twice (cause never observable — no counters). v4 uses the PROVEN
// GEMM mechanism instead: global_load_lds prefetch (fire-and-forget, no dst
// reg for the compiler to sink) into a 2x32-row LDS ring, 32-step chunks,
// one vmcnt(0)+sched_barrier drain per chunk issued AFTER ~1400 cyc of
// processing (drain ~free). Single wave -> no barriers, no races; stores
// stay compiler-managed (drain is a superset, always safe); no teardown
// hazard (final drain precedes exit).
// LDS row = 256 B (uniform base + lane*4, exactly GLL4 semantics); reads
// lbuf[r][tid] -> bank = tid%32 -> 2-way conflict = free (m136).
// ===========================================================================
__global__ __launch_bounds__(64) void lif_scan_g(
    const float* __restrict__ cur, float* __restrict__ spikes,
    float* __restrict__ vmem, float* __restrict__ vfinal,
    float* __restrict__ partials)
{
    __shared__ __align__(16) float lbuf[2][32][64];   // 16 KB

    constexpr float A_M  = 0.95122942450071400910f;
    constexpr float OM_M = 1.0f - A_M;
    constexpr float A_S  = 0.81873075307798182354f;

    const int tid   = threadIdx.x;
    const int bid   = blockIdx.x;
    const int batch = bid >> 3;                       // 32 batches
    const int hbase = (bid & 7) << 6;                 // 8 h-slices of 64
    const size_t sbase = (size_t)batch * (size_t)(Tsz * Hsz) + hbase + tid;

    const float* gsrc = cur + sbase;                  // lane column base
    float* gspk = spikes + sbase;
    float* gvmm = vmem + sbase;

    // prologue: chunk 0 (rows 0..31) -> buf 0
#pragma unroll
    for (int r = 0; r < 32; ++r)
        GLL4(gsrc + r * 512, &lbuf[0][r][0]);
    asm volatile("s_waitcnt vmcnt(0)" ::: "memory");
    __builtin_amdgcn_sched_barrier(0);

    float v = 0.f, isyn = 0.f, acc = 0.f;
    int pb = 0;
#pragma unroll 1
    for (int c = 0; c < 32; ++c) {
        if (c < 31) {                                 // prefetch next chunk
            const float* gs = gsrc + (size_t)(c + 1) * 16384;
            float (*db)[64] = lbuf[pb ^ 1];
#pragma unroll
            for (int r = 0; r < 32; ++r)
                GLL4(gs + r * 512, &db[r][0]);
        }
        const float* lrow = &lbuf[pb][0][tid];
        float* sp = gspk + (size_t)c * 16384;
        float* vp = gvmm + (size_t)c * 16384;
#pragma unroll
        for (int r = 0; r < 32; ++r) {
            const float cval = lrow[r * 64];
            isyn = fmaf(A_S, isyn, cval);
            v    = fmaf(A_M, v, OM_M * isyn);
            const bool sb = (v >= 1.0f);
            float x = fmaf(4.0f, v, -4.0f);
            x = fminf(x, 30.0f);
            const float ep = __expf(x);
            const float tt = 1.0f + ep;
            const float rr = __builtin_amdgcn_rcpf(tt * tt);
            const float spk = sb ? 1.0f : 0.0f;
            const float so = fmaf(-4.0f * ep, rr, spk + spk);
            v = sb ? 0.0f : v;
            acc += so;
            sp[r * 512] = so;
            vp[r * 512] = v;
        }
        // drain: next chunk's glds had the whole processing phase to land
        asm volatile("s_waitcnt vmcnt(0)" ::: "memory");
        __builtin_amdgcn_sched_barrier(0);
        pb ^= 1;
    }

    vfinal[bid * 64 + tid] = v;
#pragma unroll
    for (int o = 32; o; o >>= 1) acc += __shfl_down(acc, o);
    if (tid == 0) partials[blockIdx.x] = acc;
}

// ===========================================================================
// Pass 3b: LIF scan, ALIAS-SAFE fallback (cur may be the vmem region).
// ===========================================================================
__device__ __forceinline__ void lif_step(float c, float& v, float& isyn,
                                         float& so_out)
{
    constexpr float A_M  = 0.95122942450071400910f;
    constexpr float OM_M = 1.0f - A_M;
    constexpr float A_S  = 0.81873075307798182354f;
    isyn = fmaf(A_S, isyn, c);
    v    = fmaf(A_M, v, OM_M * isyn);
    const float sp = (v >= 1.0f) ? 1.0f : 0.0f;
    float x = fmaf(4.0f, v, -4.0f);
    x = fminf(x, 30.0f);
    const float ep = __expf(x);
    const float tt = 1.0f + ep;
    const float surr = 4.0f * ep * __builtin_amdgcn_rcpf(tt * tt);
    so_out = fmaf(2.0f, sp, -surr);
    v = (sp > 0.f) ? 0.0f : v;
}

__global__ __launch_bounds__(64) void lif_scan(
    const float* cur, float* spikes, float* vmem, float* vfinal, float* partials)
{
    const int tid = threadIdx.x;
    const int gid = blockIdx.x * 64 + tid;
    const size_t base = ((size_t)(gid >> 9)) * (size_t)Tsz * Hsz + (gid & 511);

    float v = 0.f, isyn = 0.f, acc = 0.f;
    constexpr int P = 8;
    float ring[P];
#pragma unroll
    for (int p = 0; p < P; ++p) ring[p] = cur[base + (size_t)p * Hsz];

    for (int t = 0; t < Tsz; t += P) {
#pragma unroll
        for (int p = 0; p < P; ++p) {
            const float c = ring[p];
            int tn = t + P + p;
            tn = tn < (Tsz - 1) ? tn : (Tsz - 1);
            ring[p] = cur[base + (size_t)tn * Hsz];

            float so;
            lif_step(c, v, isyn, so);
            const size_t idx = base + (size_t)(t + p) * Hsz;
            spikes[idx] = so;
            vmem[idx]   = v;
            acc += so;
        }
    }
    vfinal[gid] = v;
#pragma unroll
    for (int off = 32; off; off >>= 1) acc += __shfl_down(acc, off);
    if (tid == 0) partials[blockIdx.x] = acc;
}

__global__ __launch_bounds__(256) void rate_finalize(
    const float* __restrict__ partials, float* __restrict__ rate)
{
    const int tid = threadIdx.x;
    float s = partials[tid];
#pragma unroll
    for (int off = 32; off; off >>= 1) s += __shfl_down(s, off);
    __shared__ float wsum[4];
    if ((tid & 63) == 0) wsum[tid >> 6] = s;
    __syncthreads();
    if (tid == 0)
        rate[0] = ((wsum[0] + wsum[1]) + (wsum[2] + wsum[3])) * (1.0f / 16777216.0f);
}

// ===========================================================================
extern "C" void kernel_launch(void* const* d_in, const int* in_sizes, int n_in,
                              void* d_out, int out_size, void* d_ws, size_t ws_size,
                              hipStream_t stream)
{
    const float* inputs = (const float*)d_in[0];
    const float* weight = (const float*)d_in[1];
    const float* bias   = (const float*)d_in[2];

    float* out    = (float*)d_out;
    float* spikes = out;
    float* vmem   = out + ELEMS;
    float* vfinal = out + 2 * ELEMS;
    float* rate   = vfinal + (size_t)Bsz * Hsz;

    float* partials = (float*)d_ws;
    char*  ws       = (char*)d_ws;

    const size_t CUR_B = ELEMS * 4;                  // 64 MiB
    const size_t AH_B  = (size_t)Mtot * 1024 * 2;    // 64 MiB (2 fp16 limbs)
    const size_t BH_B  = (size_t)Hsz * 1024 * 2;     // 1 MiB

    _Float16 *Ah, *Bh;
    float* cur;
    int path;
    if (ws_size >= 4096 + CUR_B + AH_B + BH_B) {
        cur = (float*)(ws + 4096);
        Ah  = (_Float16*)(ws + 4096 + CUR_B);
        Bh  = Ah + (size_t)Mtot * 1024;
        path = 0;
    } else if (ws_size >= 4096 + CUR_B) {
        cur = (float*)(ws + 4096);
        Ah  = (_Float16*)d_out;                      // scan overwrites later
        Bh  = Ah + (size_t)Mtot * 1024;
        path = 1;
    } else {
        cur = vmem;
        Ah = Bh = nullptr;
        path = 2;
    }

    if (path != 2) {
        split_fp16x2<<<dim3(4096 + 256), 256, 0, stream>>>(inputs, weight, Ah, Bh);
        gemm_f16k3<<<dim3(512), 256, 0, stream>>>(Ah, Bh, bias, cur);
        lif_scan_g<<<dim3(256), 64, 0, stream>>>(cur, spikes, vmem, vfinal, partials);
    } else {
        sgemm_currents<<<dim3(4, 256), 256, 0, stream>>>(inputs, weight, bias, cur);
        lif_scan<<<dim3(256), 64, 0, stream>>>(cur, spikes, vmem, vfinal, partials);
    }
    rate_finalize<<<dim3(1), 256, 0, stream>>>(partials, rate);
}